// Round 2
// baseline (2985.673 us; speedup 1.0000x reference)
//
#include <hip/hip_runtime.h>
#include <hip/hip_bf16.h>

constexpr int B_ = 2, H_ = 256, W_ = 1216;
constexpr int HW = H_ * W_;          // 311296
constexpr int NP = B_ * HW;          // 622592
constexpr float EPS_ = 1e-6f;

typedef __hip_bfloat16 bf16;

struct alignas(8) bh4 { bf16 a, b, c, d; };

struct EpiP {
  const float* scale;
  const float* bias;
  const float* h0;
  const float* hns;
  float* outf;       // fp32 outputs (mask/conf/final)
  bf16* outh;        // bf16 outputs (h, w planes)
};

__device__ __forceinline__ float ldin(const float* p, int i) { return p[i]; }
__device__ __forceinline__ float ldin(const bf16* p, int i) { return __bfloat162float(p[i]); }

// Generic fused 3x3 SAME conv.
// Thread block = 256 threads covering a 64-wide x TY-tall tile, each thread
// computes PX consecutive x-pixels for ALL COUT channels (acc in VGPRs).
// Weights staged in LDS transposed to [cin][tap][cout].
// EPI: 0 = scale/bias + relu          -> outh = h[B,32,H,W]        (bf16)
//      1 = scale/bias + kernel norm   -> outh = w[B,COUT+1,H,W]    (bf16)
//      2 = bias + sigmoid * (h0>eps)  -> outf = mask[B,3,H,W]      (fp32)
//      3 = bias + softmax3            -> outf = conf[B,3,H,W]      (fp32)
//      4 = bias + softmax3 dot hns    -> outf = final[B,1,H,W]     (fp32)
template<int CIN, int COUT, int PX, int EPI, typename TIN>
__global__ __launch_bounds__(256)
void conv3k(const TIN* __restrict__ in0, const float* __restrict__ in1,
            const float* __restrict__ wg, EpiP p)
{
  constexpr int SPANX = 64 / PX;     // pixel groups per row
  constexpr int TY = 256 / SPANX;    // rows per block
  __shared__ float wlds[CIN * 9 * COUT];

  const int tid = threadIdx.x;
  for (int i = tid; i < CIN * 9 * COUT; i += 256) {
    int co = i % COUT;
    int r = i / COUT;
    int tap = r % 9;
    int ci = r / 9;
    wlds[i] = wg[(co * CIN + ci) * 9 + tap];   // OIHW -> [cin][tap][cout]
  }
  __syncthreads();

  const int tx = tid % SPANX, ty = tid / SPANX;
  const int x0 = blockIdx.x * 64 + tx * PX;
  const int y  = blockIdx.y * TY + ty;
  const int b  = blockIdx.z;

  float acc[COUT * PX] = {};

  for (int ci = 0; ci < CIN; ++ci) {
    float rr[3][PX + 2];
    if (CIN == 32 || ci < 32) {
      const TIN* plane = in0 + (size_t)(b * 32 + ci) * HW;
#pragma unroll
      for (int dy = 0; dy < 3; ++dy) {
        int yy = y + dy - 1;
        bool yok = (unsigned)yy < (unsigned)H_;
#pragma unroll
        for (int j = 0; j < PX + 2; ++j) {
          int xx = x0 + j - 1;
          rr[dy][j] = (yok && (unsigned)xx < (unsigned)W_) ? ldin(plane, yy * W_ + xx) : 0.f;
        }
      }
    } else {
      const float* plane = in1 + (size_t)(b * 3 + (ci - 32)) * HW;
#pragma unroll
      for (int dy = 0; dy < 3; ++dy) {
        int yy = y + dy - 1;
        bool yok = (unsigned)yy < (unsigned)H_;
#pragma unroll
        for (int j = 0; j < PX + 2; ++j) {
          int xx = x0 + j - 1;
          rr[dy][j] = (yok && (unsigned)xx < (unsigned)W_) ? plane[yy * W_ + xx] : 0.f;
        }
      }
    }
#pragma unroll
    for (int dy = 0; dy < 3; ++dy) {
#pragma unroll
      for (int dx = 0; dx < 3; ++dx) {
        const float* wrow = &wlds[(ci * 9 + dy * 3 + dx) * COUT];
#pragma unroll
        for (int co = 0; co < COUT; ++co) {
          float wv = wrow[co];
#pragma unroll
          for (int q = 0; q < PX; ++q)
            acc[co * PX + q] += rr[dy][dx + q] * wv;
        }
      }
    }
  }

  if (EPI == 0) {
    // h = relu(conv * scale + bias), bf16 NCHW store
#pragma unroll
    for (int co = 0; co < COUT; ++co) {
      float s = p.scale[co], bb = p.bias[co];
      size_t base = (size_t)(b * COUT + co) * HW + (size_t)y * W_ + x0;
      if (PX == 4) {
        bh4 v;
        v.a = __float2bfloat16(fmaxf(acc[co * PX + 0] * s + bb, 0.f));
        v.b = __float2bfloat16(fmaxf(acc[co * PX + 1] * s + bb, 0.f));
        v.c = __float2bfloat16(fmaxf(acc[co * PX + 2] * s + bb, 0.f));
        v.d = __float2bfloat16(fmaxf(acc[co * PX + 3] * s + bb, 0.f));
        *(bh4*)(p.outh + base) = v;
      } else {
#pragma unroll
        for (int q = 0; q < PX; ++q)
          p.outh[base + q] = __float2bfloat16(fmaxf(acc[co * PX + q] * s + bb, 0.f));
      }
    }
  } else if (EPI == 1) {
    // w = cbn(...); w /= (sum|w|+eps); mid = 1-sum(w); insert mid at COUT/2
    constexpr int half = COUT / 2;
#pragma unroll
    for (int q = 0; q < PX; ++q) {
      float s = EPS_;
#pragma unroll
      for (int co = 0; co < COUT; ++co) {
        float v = acc[co * PX + q] * p.scale[co] + p.bias[co];
        acc[co * PX + q] = v;
        s += fabsf(v);
      }
      float inv = 1.f / s;
      float sm = 0.f;
      size_t base = (size_t)b * (COUT + 1) * HW + (size_t)y * W_ + x0 + q;
#pragma unroll
      for (int co = 0; co < COUT; ++co) {
        float vn = acc[co * PX + q] * inv;
        sm += vn;
        int ch = (co < half) ? co : co + 1;
        p.outh[base + (size_t)ch * HW] = __float2bfloat16(vn);
      }
      p.outh[base + (size_t)half * HW] = __float2bfloat16(1.f - sm);
    }
  } else if (EPI == 2) {
    // mask = sigmoid(conv + bias) * (h0 > 0.001)
#pragma unroll
    for (int q = 0; q < PX; ++q) {
      float h0v = p.h0[(size_t)b * HW + (size_t)y * W_ + x0 + q];
      float valid = (h0v > 0.001f) ? 1.f : 0.f;
#pragma unroll
      for (int co = 0; co < COUT; ++co) {
        float v = acc[co * PX + q] + p.bias[co];
        float sg = 1.f / (1.f + expf(-v));
        p.outf[(size_t)(b * 3 + co) * HW + (size_t)y * W_ + x0 + q] = sg * valid;
      }
    }
  } else if (EPI == 3) {
    // conf = softmax3(conv + bias)
#pragma unroll
    for (int q = 0; q < PX; ++q) {
      float v0 = acc[0 * PX + q] + p.bias[0];
      float v1 = acc[1 * PX + q] + p.bias[1];
      float v2 = acc[2 * PX + q] + p.bias[2];
      float m = fmaxf(v0, fmaxf(v1, v2));
      float e0 = expf(v0 - m), e1 = expf(v1 - m), e2 = expf(v2 - m);
      float inv = 1.f / (e0 + e1 + e2);
      size_t base = (size_t)b * 3 * HW + (size_t)y * W_ + x0 + q;
      p.outf[base + 0 * (size_t)HW] = e0 * inv;
      p.outf[base + 1 * (size_t)HW] = e1 * inv;
      p.outf[base + 2 * (size_t)HW] = e2 * inv;
    }
  } else if (EPI == 4) {
    // wt = softmax3(conv + bias); out = sum(wt * hns)
#pragma unroll
    for (int q = 0; q < PX; ++q) {
      float v0 = acc[0 * PX + q] + p.bias[0];
      float v1 = acc[1 * PX + q] + p.bias[1];
      float v2 = acc[2 * PX + q] + p.bias[2];
      float m = fmaxf(v0, fmaxf(v1, v2));
      float e0 = expf(v0 - m), e1 = expf(v1 - m), e2 = expf(v2 - m);
      float inv = 1.f / (e0 + e1 + e2);
      size_t pix = (size_t)y * W_ + x0 + q;
      float a0 = p.hns[(size_t)(b * 3 + 0) * HW + pix];
      float a1 = p.hns[(size_t)(b * 3 + 1) * HW + pix];
      float a2 = p.hns[(size_t)(b * 3 + 2) * HW + pix];
      p.outf[(size_t)b * HW + pix] = (e0 * a0 + e1 * a1 + e2 * a2) * inv;
    }
  }
}

// h3 = h5 = h7 = hn; hns[ch0] = hn
__global__ __launch_bounds__(256)
void init_k(const float* __restrict__ hn, float* __restrict__ h3,
            float* __restrict__ h5, float* __restrict__ h7,
            float* __restrict__ hns)
{
  int t = blockIdx.x * 256 + threadIdx.x;
  if (t >= NP) return;
  float v = hn[t];
  h3[t] = v; h5[t] = v; h7[t] = v;
  int b = t / HW, rem = t - b * HW;
  hns[(size_t)b * 3 * HW + rem] = v;
}

// One propagation step for all three scales; optionally writes the
// confidence-combined map into hns channel `chn`.
__global__ __launch_bounds__(256)
void iterate_k(const float* __restrict__ h3i, const float* __restrict__ h5i,
               const float* __restrict__ h7i,
               float* __restrict__ h3o, float* __restrict__ h5o,
               float* __restrict__ h7o,
               const bf16* __restrict__ w3, const bf16* __restrict__ w5,
               const bf16* __restrict__ w7,
               const float* __restrict__ mask, const float* __restrict__ h0,
               float* __restrict__ hns, int chn, const float* __restrict__ conf)
{
  int t = blockIdx.x * 256 + threadIdx.x;
  if (t >= NP) return;
  int b = t / HW;
  int rem = t - b * HW;
  int y = rem / W_;
  int x = rem - y * W_;
  size_t pb = (size_t)b * HW;

  float h0v = h0[t];

  // 3x3
  float s3 = 0.f;
#pragma unroll
  for (int k = 0; k < 9; ++k) {
    int dy = k / 3 - 1, dx = k % 3 - 1;
    int yy = y + dy, xx = x + dx;
    float hv = ((unsigned)yy < (unsigned)H_ && (unsigned)xx < (unsigned)W_)
                   ? h3i[pb + yy * W_ + xx] : 0.f;
    s3 += hv * __bfloat162float(w3[(size_t)(b * 9 + k) * HW + rem]);
  }
  float m3 = mask[(size_t)(b * 3 + 0) * HW + rem];
  float n3 = (1.f - m3) * s3 + m3 * h0v;
  h3o[t] = n3;

  // 5x5
  float s5 = 0.f;
#pragma unroll
  for (int k = 0; k < 25; ++k) {
    int dy = k / 5 - 2, dx = k % 5 - 2;
    int yy = y + dy, xx = x + dx;
    float hv = ((unsigned)yy < (unsigned)H_ && (unsigned)xx < (unsigned)W_)
                   ? h5i[pb + yy * W_ + xx] : 0.f;
    s5 += hv * __bfloat162float(w5[(size_t)(b * 25 + k) * HW + rem]);
  }
  float m5 = mask[(size_t)(b * 3 + 1) * HW + rem];
  float n5 = (1.f - m5) * s5 + m5 * h0v;
  h5o[t] = n5;

  // 7x7
  float s7 = 0.f;
#pragma unroll
  for (int k = 0; k < 49; ++k) {
    int dy = k / 7 - 3, dx = k % 7 - 3;
    int yy = y + dy, xx = x + dx;
    float hv = ((unsigned)yy < (unsigned)H_ && (unsigned)xx < (unsigned)W_)
                   ? h7i[pb + yy * W_ + xx] : 0.f;
    s7 += hv * __bfloat162float(w7[(size_t)(b * 49 + k) * HW + rem]);
  }
  float m7 = mask[(size_t)(b * 3 + 2) * HW + rem];
  float n7 = (1.f - m7) * s7 + m7 * h0v;
  h7o[t] = n7;

  if (chn >= 0) {
    float c3 = conf[(size_t)(b * 3 + 0) * HW + rem];
    float c5 = conf[(size_t)(b * 3 + 1) * HW + rem];
    float c7 = conf[(size_t)(b * 3 + 2) * HW + rem];
    hns[(size_t)(b * 3 + chn) * HW + rem] = c3 * n3 + c5 * n5 + c7 * n7;
  }
}

extern "C" void kernel_launch(void* const* d_in, const int* in_sizes, int n_in,
                              void* d_out, int out_size, void* d_ws, size_t ws_size,
                              hipStream_t stream) {
  const float* fout = (const float*)d_in[0];
  const float* hn   = (const float*)d_in[1];
  const float* h0   = (const float*)d_in[2];
  const float* k3w1 = (const float*)d_in[3];
  const float* k3s1 = (const float*)d_in[4];
  const float* k3b1 = (const float*)d_in[5];
  const float* k3w2 = (const float*)d_in[6];
  const float* k3s2 = (const float*)d_in[7];
  const float* k3b2 = (const float*)d_in[8];
  const float* k5w1 = (const float*)d_in[9];
  const float* k5s1 = (const float*)d_in[10];
  const float* k5b1 = (const float*)d_in[11];
  const float* k5w2 = (const float*)d_in[12];
  const float* k5s2 = (const float*)d_in[13];
  const float* k5b2 = (const float*)d_in[14];
  const float* k7w1 = (const float*)d_in[15];
  const float* k7s1 = (const float*)d_in[16];
  const float* k7b1 = (const float*)d_in[17];
  const float* k7w2 = (const float*)d_in[18];
  const float* k7s2 = (const float*)d_in[19];
  const float* k7b2 = (const float*)d_in[20];
  const float* mw1  = (const float*)d_in[21];
  const float* ms1  = (const float*)d_in[22];
  const float* mb1  = (const float*)d_in[23];
  const float* mw2  = (const float*)d_in[24];
  const float* mbias2 = (const float*)d_in[25];
  const float* cw1  = (const float*)d_in[26];
  const float* cs1  = (const float*)d_in[27];
  const float* cb1  = (const float*)d_in[28];
  const float* cw2  = (const float*)d_in[29];
  const float* cbias2 = (const float*)d_in[30];
  const float* tw1  = (const float*)d_in[31];
  const float* ts1  = (const float*)d_in[32];
  const float* tb1  = (const float*)d_in[33];
  const float* tw2  = (const float*)d_in[34];
  const float* tbias2 = (const float*)d_in[35];

  float* out = (float*)d_out;
  float* ws = (float*)d_ws;

  // fp32 region: 15 NP-planes; bf16 region: 115 NP-planes.
  // Total = 15*4 + 115*2 = 290 bytes/pixel * 622592 = ~180.5 MB
  size_t need = (size_t)NP * (15 * 4 + 115 * 2);
  if (ws_size < need) return;  // clean diagnostic failure instead of OOB fault

  float* mask = ws;                          // 3*NP f32
  float* conf = mask + (size_t)3 * NP;       // 3*NP f32
  float* hA   = conf + (size_t)3 * NP;       // 6*NP f32 (3 ping-pong pairs)
  float* hns  = hA   + (size_t)6 * NP;       // 3*NP f32
  bf16* h  = (bf16*)(hns + (size_t)3 * NP);  // 32*NP bf16
  bf16* w3 = h  + (size_t)32 * NP;           // 9*NP bf16
  bf16* w5 = w3 + (size_t)9 * NP;            // 25*NP bf16
  bf16* w7 = w5 + (size_t)25 * NP;           // 49*NP bf16

  dim3 blk(256);
  dim3 g4(W_ / 64, H_ / 16, B_);   // PX=4 tiles
  dim3 g2(W_ / 64, H_ / 8, B_);    // PX=2 tiles
  dim3 ge((NP + 255) / 256);

  EpiP p;

  // --- kernel-generator branches: conv1(relu) -> conv2(gen normalize) ---
  p = {}; p.scale = k3s1; p.bias = k3b1; p.outh = h;
  conv3k<32, 32, 4, 0, float><<<g4, blk, 0, stream>>>(fout, nullptr, k3w1, p);
  p = {}; p.scale = k3s2; p.bias = k3b2; p.outh = w3;
  conv3k<32, 8, 4, 1, bf16><<<g4, blk, 0, stream>>>(h, nullptr, k3w2, p);

  p = {}; p.scale = k5s1; p.bias = k5b1; p.outh = h;
  conv3k<32, 32, 4, 0, float><<<g4, blk, 0, stream>>>(fout, nullptr, k5w1, p);
  p = {}; p.scale = k5s2; p.bias = k5b2; p.outh = w5;
  conv3k<32, 24, 4, 1, bf16><<<g4, blk, 0, stream>>>(h, nullptr, k5w2, p);

  p = {}; p.scale = k7s1; p.bias = k7b1; p.outh = h;
  conv3k<32, 32, 4, 0, float><<<g4, blk, 0, stream>>>(fout, nullptr, k7w1, p);
  p = {}; p.scale = k7s2; p.bias = k7b2; p.outh = w7;
  conv3k<32, 48, 2, 1, bf16><<<g2, blk, 0, stream>>>(h, nullptr, k7w2, p);

  // --- mask branch ---
  p = {}; p.scale = ms1; p.bias = mb1; p.outh = h;
  conv3k<32, 32, 4, 0, float><<<g4, blk, 0, stream>>>(fout, nullptr, mw1, p);
  p = {}; p.bias = mbias2; p.h0 = h0; p.outf = mask;
  conv3k<32, 3, 4, 2, bf16><<<g4, blk, 0, stream>>>(h, nullptr, mw2, p);

  // --- confidence branch ---
  p = {}; p.scale = cs1; p.bias = cb1; p.outh = h;
  conv3k<32, 32, 4, 0, float><<<g4, blk, 0, stream>>>(fout, nullptr, cw1, p);
  p = {}; p.bias = cbias2; p.outf = conf;
  conv3k<32, 3, 4, 3, bf16><<<g4, blk, 0, stream>>>(h, nullptr, cw2, p);

  // --- propagation ---
  float* h3c = hA + (size_t)0 * NP; float* h3n = hA + (size_t)1 * NP;
  float* h5c = hA + (size_t)2 * NP; float* h5n = hA + (size_t)3 * NP;
  float* h7c = hA + (size_t)4 * NP; float* h7n = hA + (size_t)5 * NP;

  init_k<<<ge, blk, 0, stream>>>(hn, h3c, h5c, h7c, hns);

  for (int i = 0; i < 6; ++i) {
    int chn = (i == 2) ? 1 : ((i == 5) ? 2 : -1);
    iterate_k<<<ge, blk, 0, stream>>>(h3c, h5c, h7c, h3n, h5n, h7n,
                                      w3, w5, w7, mask, h0, hns, chn, conf);
    float* t;
    t = h3c; h3c = h3n; h3n = t;
    t = h5c; h5c = h5n; h5n = t;
    t = h7c; h7c = h7n; h7n = t;
  }

  // --- final temporal-weight branch: conv1 over concat([fout, hns]) ---
  p = {}; p.scale = ts1; p.bias = tb1; p.outh = h;
  conv3k<35, 32, 4, 0, float><<<g4, blk, 0, stream>>>(fout, hns, tw1, p);
  p = {}; p.bias = tbias2; p.hns = hns; p.outf = out;
  conv3k<32, 3, 4, 4, bf16><<<g4, blk, 0, stream>>>(h, nullptr, tw2, p);
}

// Round 5
// 1199.778 us; speedup vs baseline: 2.4885x; 2.4885x over previous
//
#include <hip/hip_runtime.h>
#include <hip/hip_bf16.h>

constexpr int B_ = 2, H_ = 256, W_ = 1216;
constexpr int HW = H_ * W_;          // 311296
constexpr int NP = B_ * HW;          // 622592
constexpr float EPS_ = 1e-6f;

typedef __bf16 bfrag __attribute__((ext_vector_type(8)));
typedef float f4 __attribute__((ext_vector_type(4)));

union BU { uint4 u; bfrag f; };

__device__ __forceinline__ ushort f2b(float x) {
  uint u = __float_as_uint(x);
  u += 0x7fffu + ((u >> 16) & 1u);
  return (ushort)(u >> 16);
}
__device__ __forceinline__ float b2f(ushort u) {
  return __uint_as_float(((uint)u) << 16);
}

// ---------------------------------------------------------------------------
// Split-precision conv1 for the w-chains: fout(fp32 NCHW) -> h(bf16 NHWC).
// fp32-grade via hi/lo bf16: acc = Whi*Xhi + Whi*Xlo + Wlo*Xhi (3 MFMA/tap).
// LDS phase A: weights hi/lo; regs; barrier; phase B: same buffer holds the
// hi/lo input tile. CIN=COUT=32, nM=2.
// ---------------------------------------------------------------------------
__global__ __launch_bounds__(256, 2)
void convs1(const float* __restrict__ xf, const float* __restrict__ wg,
            const float* __restrict__ scale, const float* __restrict__ bias,
            ushort* __restrict__ outh)
{
  __shared__ ushort buf[25344];   // max(wl 18432, xl 25344) ushorts = 50.7 KB

  const int tid = threadIdx.x;
  const int lane = tid & 63;
  const int wid = tid >> 6;
  const int x0 = blockIdx.x * 64, y0 = blockIdx.y * 4, b = blockIdx.z;

  // phase A: weights OIHW fp32 -> [tap][co][ci] hi (buf[0..9216)) / lo (+9216)
  for (int i = tid; i < 9 * 32 * 32; i += 256) {
    int ci = i & 31, rest = i >> 5;
    int co = rest & 31, tap = rest >> 5;
    float v = wg[(co * 32 + ci) * 9 + tap];
    ushort hi = f2b(v);
    ushort lo = f2b(v - b2f(hi));
    int idx = (tap * 32 + co) * 32 + ci;
    buf[idx] = hi;
    buf[9216 + idx] = lo;
  }
  __syncthreads();

  bfrag avhi[2][9], avlo[2][9];
#pragma unroll
  for (int tap = 0; tap < 9; ++tap)
#pragma unroll
    for (int mt = 0; mt < 2; ++mt) {
      int idx = ((tap * 32) + mt * 16 + (lane & 15)) * 32 + (lane >> 4) * 8;
      avhi[mt][tap] = *(const bfrag*)&buf[idx];
      avlo[mt][tap] = *(const bfrag*)&buf[9216 + idx];
    }
  __syncthreads();

  // phase B: input tile rows y0-1..y0+4, cols x0-1..x0+64, hi at [0..12672),
  // lo at [12672..25344), layout [pix][ci]
  for (int i = tid; i < 396 * 4; i += 256) {
    int oct = i & 3, rest = i >> 2;
    int xx = rest % 66, rr = rest / 66;
    int yy = y0 - 1 + rr, x = x0 - 1 + xx;
    uint4 vh = {0, 0, 0, 0}, vl = {0, 0, 0, 0};
    if ((unsigned)yy < (unsigned)H_ && (unsigned)x < (unsigned)W_) {
      const float* src = xf + ((size_t)b * 32 + oct * 8) * HW + (size_t)yy * W_ + x;
      uint uh[4], ul[4];
#pragma unroll
      for (int j = 0; j < 4; ++j) {
        float a = src[(size_t)(2 * j + 0) * HW];
        float c = src[(size_t)(2 * j + 1) * HW];
        ushort ah = f2b(a), ch = f2b(c);
        ushort al = f2b(a - b2f(ah)), cl = f2b(c - b2f(ch));
        uh[j] = (uint)ah | ((uint)ch << 16);
        ul[j] = (uint)al | ((uint)cl << 16);
      }
      vh = uint4{uh[0], uh[1], uh[2], uh[3]};
      vl = uint4{ul[0], ul[1], ul[2], ul[3]};
    }
    *(uint4*)&buf[rest * 32 + oct * 8] = vh;
    *(uint4*)&buf[12672 + rest * 32 + oct * 8] = vl;
  }
  __syncthreads();

  const int n = lane & 15, quad = lane >> 4;

  for (int t = wid; t < 16; t += 4) {
    int r = t >> 2, g = t & 3;
    f4 acc[2] = {f4{0.f, 0.f, 0.f, 0.f}, f4{0.f, 0.f, 0.f, 0.f}};
#pragma unroll
    for (int tap = 0; tap < 9; ++tap) {
      int dy = tap / 3, dx = tap % 3;
      int pix = (r + dy) * 66 + g * 16 + n + dx;
      bfrag bhi = *(const bfrag*)&buf[pix * 32 + quad * 8];
      bfrag blo = *(const bfrag*)&buf[12672 + pix * 32 + quad * 8];
#pragma unroll
      for (int mt = 0; mt < 2; ++mt) {
        acc[mt] = __builtin_amdgcn_mfma_f32_16x16x32_bf16(avhi[mt][tap], bhi, acc[mt], 0, 0, 0);
        acc[mt] = __builtin_amdgcn_mfma_f32_16x16x32_bf16(avhi[mt][tap], blo, acc[mt], 0, 0, 0);
        acc[mt] = __builtin_amdgcn_mfma_f32_16x16x32_bf16(avlo[mt][tap], bhi, acc[mt], 0, 0, 0);
      }
    }
    int gx = x0 + g * 16 + n, gy = y0 + r;
    size_t bpix = (size_t)b * HW + (size_t)gy * W_ + gx;
#pragma unroll
    for (int mt = 0; mt < 2; ++mt) {
      int cob = mt * 16 + quad * 4;
      float v0 = fmaxf(acc[mt][0] * scale[cob + 0] + bias[cob + 0], 0.f);
      float v1 = fmaxf(acc[mt][1] * scale[cob + 1] + bias[cob + 1], 0.f);
      float v2 = fmaxf(acc[mt][2] * scale[cob + 2] + bias[cob + 2], 0.f);
      float v3 = fmaxf(acc[mt][3] * scale[cob + 3] + bias[cob + 3], 0.f);
      uint u0 = (uint)f2b(v0) | ((uint)f2b(v1) << 16);
      uint u1 = (uint)f2b(v2) | ((uint)f2b(v3) << 16);
      *(uint2*)&outh[bpix * 32 + cob] = uint2{u0, u1};
    }
  }
}

// ---------------------------------------------------------------------------
// Split-precision conv2 for the w-chains: h(bf16 NHWC, EXACT) -> w planes.
// Input exact => only weight split needed: acc = Whi*X + Wlo*X (2 MFMA/tap).
// LDS: [wl_lo (persistent) | union(wl_hi, xl)]; Ahi cached in regs, Alo read
// from LDS during compute. Epilogue: gen-kernel normalize, NO mid plane.
// ---------------------------------------------------------------------------
template<int nM, int MINW>
__global__ __launch_bounds__(256, MINW)
void convs2(const ushort* __restrict__ xh, const float* __restrict__ wg,
            const float* __restrict__ scale, const float* __restrict__ bias,
            ushort* __restrict__ outw, int CO)
{
  constexpr int NM16 = nM * 16;
  constexpr int WSZ = 9 * NM16 * 32;
  constexpr int R2 = (WSZ > 12672) ? WSZ : 12672;
  __shared__ ushort buf[WSZ + R2];   // nM=3: 55.3 KB

  const int tid = threadIdx.x;
  const int lane = tid & 63;
  const int wid = tid >> 6;
  const int x0 = blockIdx.x * 64, y0 = blockIdx.y * 4, b = blockIdx.z;

  // phase A: weights -> lo at buf[0..WSZ), hi at buf[WSZ..WSZ+WSZ)
  for (int i = tid; i < WSZ; i += 256) {
    int ci = i & 31, rest = i >> 5;
    int co = rest % NM16, tap = rest / NM16;
    float v = (co < CO) ? wg[(co * 32 + ci) * 9 + tap] : 0.f;
    ushort hi = f2b(v);
    ushort lo = f2b(v - b2f(hi));
    buf[i] = lo;
    buf[WSZ + i] = hi;
  }
  __syncthreads();

  bfrag avhi[nM][9];
#pragma unroll
  for (int tap = 0; tap < 9; ++tap)
#pragma unroll
    for (int mt = 0; mt < nM; ++mt)
      avhi[mt][tap] = *(const bfrag*)&buf[WSZ + ((tap * NM16) + mt * 16 + (lane & 15)) * 32 + (lane >> 4) * 8];
  __syncthreads();

  // phase B: input tile (bf16 NHWC) into buf[WSZ..WSZ+12672)
  for (int i = tid; i < 396 * 4; i += 256) {
    int oct = i & 3, rest = i >> 2;
    int xx = rest % 66, rr = rest / 66;
    int yy = y0 - 1 + rr, x = x0 - 1 + xx;
    uint4 v = {0, 0, 0, 0};
    if ((unsigned)yy < (unsigned)H_ && (unsigned)x < (unsigned)W_)
      v = *(const uint4*)&xh[((size_t)b * HW + (size_t)yy * W_ + x) * 32 + oct * 8];
    *(uint4*)&buf[WSZ + rest * 32 + oct * 8] = v;
  }
  __syncthreads();

  const int n = lane & 15, quad = lane >> 4;

  for (int t = wid; t < 16; t += 4) {
    int r = t >> 2, g = t & 3;
    f4 acc[nM];
#pragma unroll
    for (int mt = 0; mt < nM; ++mt) acc[mt] = f4{0.f, 0.f, 0.f, 0.f};

#pragma unroll
    for (int tap = 0; tap < 9; ++tap) {
      int dy = tap / 3, dx = tap % 3;
      int pix = (r + dy) * 66 + g * 16 + n + dx;
      bfrag bv = *(const bfrag*)&buf[WSZ + pix * 32 + quad * 8];
#pragma unroll
      for (int mt = 0; mt < nM; ++mt) {
        bfrag alo = *(const bfrag*)&buf[((tap * NM16) + mt * 16 + (lane & 15)) * 32 + (lane >> 4) * 8];
        acc[mt] = __builtin_amdgcn_mfma_f32_16x16x32_bf16(avhi[mt][tap], bv, acc[mt], 0, 0, 0);
        acc[mt] = __builtin_amdgcn_mfma_f32_16x16x32_bf16(alo, bv, acc[mt], 0, 0, 0);
      }
    }

    int gx = x0 + g * 16 + n, gy = y0 + r;
    size_t gpix = (size_t)gy * W_ + gx;

    // gen-kernel normalize epilogue (mid not stored)
    float vs[nM][4];
    float pa = 0.f;
#pragma unroll
    for (int mt = 0; mt < nM; ++mt)
#pragma unroll
      for (int rg = 0; rg < 4; ++rg) {
        int co = mt * 16 + quad * 4 + rg;
        float v = (co < CO) ? acc[mt][rg] * scale[co] + bias[co] : 0.f;
        vs[mt][rg] = v;
        pa += fabsf(v);
      }
    pa += __shfl_xor(pa, 16);
    pa += __shfl_xor(pa, 32);
    float inv = 1.f / (pa + EPS_);
#pragma unroll
    for (int mt = 0; mt < nM; ++mt)
#pragma unroll
      for (int rg = 0; rg < 4; ++rg) {
        int co = mt * 16 + quad * 4 + rg;
        if (co < CO)
          outw[((size_t)b * CO + co) * HW + gpix] = f2b(vs[mt][rg] * inv);
      }
  }
}

// ---------------------------------------------------------------------------
// Plain bf16 MFMA conv (mask/conf/t branches). Same as R4.
// EPI: 0 relu*scale+bias -> outw NHWC bf16 (h)
//      2 sigmoid(conv+bias)*(h0>.001) -> outf 3 fp32 planes (mask)
//      3 softmax3(conv+bias) -> outf 3 fp32 planes (conf)
//      4 softmax3(conv+bias) dot hns -> outf fp32 [B][HW] (final)
// KB2: extra K-block for channels 32..34 (hns fp32), hi/lo packed in K-lanes.
// ---------------------------------------------------------------------------
template<int nM, int EPI, int KB2, int NCHWIN, int MINW>
__global__ __launch_bounds__(256, MINW)
void convmf(const float* __restrict__ xf, const ushort* __restrict__ xh,
            const float* __restrict__ hnsp,
            const float* __restrict__ wg, const float* __restrict__ scale,
            const float* __restrict__ bias, const float* __restrict__ h0,
            ushort* __restrict__ outw, float* __restrict__ outf, int CO)
{
  constexpr int NM16 = nM * 16;
  constexpr int CIN = KB2 ? 35 : 32;
  __shared__ ushort wl[9 * NM16 * 32];
  __shared__ ushort xl[396 * 32];
  __shared__ ushort wl2[KB2 ? 9 * 32 * 8 : 8];
  __shared__ ushort xl2[KB2 ? 396 * 8 : 8];

  const int tid = threadIdx.x;
  const int lane = tid & 63;
  const int wid = tid >> 6;
  const int x0 = blockIdx.x * 64, y0 = blockIdx.y * 4, b = blockIdx.z;

  for (int i = tid; i < 9 * NM16 * 32; i += 256) {
    int ci = i & 31, rest = i >> 5;
    int co = rest % NM16, tap = rest / NM16;
    float v = (co < CO) ? wg[(co * CIN + ci) * 9 + tap] : 0.f;
    wl[(tap * NM16 + co) * 32 + ci] = f2b(v);
  }
  if (KB2) {
    for (int i = tid; i < 9 * 32 * 8; i += 256) {
      int c8 = i & 7, rest = i >> 3;
      int co = rest & 31, tap = rest >> 5;
      int cc = (c8 < 3) ? c8 : ((c8 < 6) ? c8 - 3 : -1);
      float v = (cc >= 0) ? wg[(co * 35 + 32 + cc) * 9 + tap] : 0.f;
      wl2[(tap * 32 + co) * 8 + c8] = f2b(v);
    }
    for (int i = tid; i < 396; i += 256) {
      int xx = i % 66, rr = i / 66;
      int yy = y0 - 1 + rr, x = x0 - 1 + xx;
      float v0 = 0.f, v1 = 0.f, v2 = 0.f;
      if ((unsigned)yy < (unsigned)H_ && (unsigned)x < (unsigned)W_) {
        size_t pix = (size_t)yy * W_ + x;
        v0 = hnsp[((size_t)b * 3 + 0) * HW + pix];
        v1 = hnsp[((size_t)b * 3 + 1) * HW + pix];
        v2 = hnsp[((size_t)b * 3 + 2) * HW + pix];
      }
      ushort h0b = f2b(v0), h1b = f2b(v1), h2b = f2b(v2);
      ushort l0 = f2b(v0 - b2f(h0b)), l1 = f2b(v1 - b2f(h1b)), l2 = f2b(v2 - b2f(h2b));
      uint u0 = (uint)h0b | ((uint)h1b << 16);
      uint u1 = (uint)h2b | ((uint)l0 << 16);
      uint u2 = (uint)l1 | ((uint)l2 << 16);
      *(uint4*)&xl2[i * 8] = uint4{u0, u1, u2, 0};
    }
  }
  if (NCHWIN) {
    for (int i = tid; i < 396 * 4; i += 256) {
      int oct = i & 3, rest = i >> 2;
      int xx = rest % 66, rr = rest / 66;
      int yy = y0 - 1 + rr, x = x0 - 1 + xx;
      uint4 v = {0, 0, 0, 0};
      if ((unsigned)yy < (unsigned)H_ && (unsigned)x < (unsigned)W_) {
        const float* src = xf + ((size_t)b * 32 + oct * 8) * HW + (size_t)yy * W_ + x;
        uint u[4];
#pragma unroll
        for (int j = 0; j < 4; ++j) {
          float a = src[(size_t)(2 * j + 0) * HW];
          float c = src[(size_t)(2 * j + 1) * HW];
          u[j] = (uint)f2b(a) | ((uint)f2b(c) << 16);
        }
        v = uint4{u[0], u[1], u[2], u[3]};
      }
      *(uint4*)&xl[rest * 32 + oct * 8] = v;
    }
  } else {
    for (int i = tid; i < 396 * 4; i += 256) {
      int oct = i & 3, rest = i >> 2;
      int xx = rest % 66, rr = rest / 66;
      int yy = y0 - 1 + rr, x = x0 - 1 + xx;
      uint4 v = {0, 0, 0, 0};
      if ((unsigned)yy < (unsigned)H_ && (unsigned)x < (unsigned)W_)
        v = *(const uint4*)&xh[((size_t)b * HW + (size_t)yy * W_ + x) * 32 + oct * 8];
      *(uint4*)&xl[rest * 32 + oct * 8] = v;
    }
  }
  __syncthreads();

  bfrag av[nM][9];
#pragma unroll
  for (int tap = 0; tap < 9; ++tap)
#pragma unroll
    for (int mt = 0; mt < nM; ++mt)
      av[mt][tap] = *(const bfrag*)&wl[((tap * NM16) + mt * 16 + (lane & 15)) * 32 + (lane >> 4) * 8];
  bfrag a2[KB2 ? nM : 1][KB2 ? 9 : 1];
  if (KB2) {
#pragma unroll
    for (int tap = 0; tap < 9; ++tap)
#pragma unroll
      for (int mt = 0; mt < nM; ++mt) {
        BU t; t.u = uint4{0, 0, 0, 0};
        if (lane < 16) t.f = *(const bfrag*)&wl2[(tap * 32 + mt * 16 + lane) * 8];
        a2[mt][tap] = t.f;
      }
  }

  const int n = lane & 15, quad = lane >> 4;

  for (int t = wid; t < 16; t += 4) {
    int r = t >> 2, g = t & 3;
    f4 acc[nM];
#pragma unroll
    for (int mt = 0; mt < nM; ++mt) acc[mt] = f4{0.f, 0.f, 0.f, 0.f};

#pragma unroll
    for (int tap = 0; tap < 9; ++tap) {
      int dy = tap / 3, dx = tap % 3;
      int pix = (r + dy) * 66 + g * 16 + n + dx;
      bfrag bv = *(const bfrag*)&xl[pix * 32 + quad * 8];
#pragma unroll
      for (int mt = 0; mt < nM; ++mt)
        acc[mt] = __builtin_amdgcn_mfma_f32_16x16x32_bf16(av[mt][tap], bv, acc[mt], 0, 0, 0);
      if (KB2) {
        BU t2; t2.u = uint4{0, 0, 0, 0};
        if (lane < 16) t2.f = *(const bfrag*)&xl2[pix * 8];
#pragma unroll
        for (int mt = 0; mt < nM; ++mt)
          acc[mt] = __builtin_amdgcn_mfma_f32_16x16x32_bf16(a2[mt][tap], t2.f, acc[mt], 0, 0, 0);
      }
    }

    int gx = x0 + g * 16 + n, gy = y0 + r;
    size_t gpix = (size_t)gy * W_ + gx;
    size_t bpix = (size_t)b * HW + gpix;

    if constexpr (EPI == 0) {
#pragma unroll
      for (int mt = 0; mt < nM; ++mt) {
        int cob = mt * 16 + quad * 4;
        float v0 = fmaxf(acc[mt][0] * scale[cob + 0] + bias[cob + 0], 0.f);
        float v1 = fmaxf(acc[mt][1] * scale[cob + 1] + bias[cob + 1], 0.f);
        float v2 = fmaxf(acc[mt][2] * scale[cob + 2] + bias[cob + 2], 0.f);
        float v3 = fmaxf(acc[mt][3] * scale[cob + 3] + bias[cob + 3], 0.f);
        uint u0 = (uint)f2b(v0) | ((uint)f2b(v1) << 16);
        uint u1 = (uint)f2b(v2) | ((uint)f2b(v3) << 16);
        *(uint2*)&outw[bpix * 32 + cob] = uint2{u0, u1};
      }
    } else if constexpr (EPI == 2) {
      if (lane < 16) {
        float valid = (h0[bpix] > 0.001f) ? 1.f : 0.f;
#pragma unroll
        for (int rg = 0; rg < 3; ++rg) {
          float v = acc[0][rg] + bias[rg];
          float sg = 1.f / (1.f + expf(-v));
          outf[((size_t)b * 3 + rg) * HW + gpix] = sg * valid;
        }
      }
    } else if constexpr (EPI == 3) {
      if (lane < 16) {
        float v0 = acc[0][0] + bias[0];
        float v1 = acc[0][1] + bias[1];
        float v2 = acc[0][2] + bias[2];
        float m = fmaxf(v0, fmaxf(v1, v2));
        float e0 = expf(v0 - m), e1 = expf(v1 - m), e2 = expf(v2 - m);
        float inv = 1.f / (e0 + e1 + e2);
        outf[((size_t)b * 3 + 0) * HW + gpix] = e0 * inv;
        outf[((size_t)b * 3 + 1) * HW + gpix] = e1 * inv;
        outf[((size_t)b * 3 + 2) * HW + gpix] = e2 * inv;
      }
    } else if constexpr (EPI == 4) {
      if (lane < 16) {
        float v0 = acc[0][0] + bias[0];
        float v1 = acc[0][1] + bias[1];
        float v2 = acc[0][2] + bias[2];
        float m = fmaxf(v0, fmaxf(v1, v2));
        float e0 = expf(v0 - m), e1 = expf(v1 - m), e2 = expf(v2 - m);
        float inv = 1.f / (e0 + e1 + e2);
        float a0 = hnsp[((size_t)b * 3 + 0) * HW + gpix];
        float a1 = hnsp[((size_t)b * 3 + 1) * HW + gpix];
        float a2v = hnsp[((size_t)b * 3 + 2) * HW + gpix];
        outf[bpix] = (e0 * a0 + e1 * a1 + e2 * a2v) * inv;
      }
    }
  }
}

// ---------------------------------------------------------------------------
__global__ __launch_bounds__(256)
void init_k(const float* __restrict__ hn, float* __restrict__ h3,
            float* __restrict__ h5, float* __restrict__ h7,
            float* __restrict__ hns)
{
  int t = blockIdx.x * 256 + threadIdx.x;
  if (t >= NP) return;
  float v = hn[t];
  h3[t] = v; h5[t] = v; h7[t] = v;
  int b = t / HW, rem = t - b * HW;
  hns[(size_t)b * 3 * HW + rem] = v;
}

// ---------------------------------------------------------------------------
// Propagation step. w planes bf16 w/o mid; mid = 1 - sum (fp32 recompute).
// State fp32 (values reach ~200; bf16 state was the R3 failure).
// ---------------------------------------------------------------------------
__global__ __launch_bounds__(256)
void iterate_k(const float* __restrict__ h3i, const float* __restrict__ h5i,
               const float* __restrict__ h7i,
               float* __restrict__ h3o, float* __restrict__ h5o,
               float* __restrict__ h7o,
               const ushort* __restrict__ w3, const ushort* __restrict__ w5,
               const ushort* __restrict__ w7,
               const float* __restrict__ mask, const float* __restrict__ h0,
               float* __restrict__ hns, int chn, const float* __restrict__ conf)
{
  int t = blockIdx.x * 256 + threadIdx.x;
  if (t >= NP) return;
  int b = t / HW;
  int rem = t - b * HW;
  int y = rem / W_;
  int x = rem - y * W_;
  size_t pb = (size_t)b * HW;

  float h0v = h0[t];

  float s3 = 0.f, ws3 = 0.f;
#pragma unroll
  for (int p = 0; p < 8; ++p) {
    int tap = (p < 4) ? p : p + 1;
    int dy = tap / 3 - 1, dx = tap % 3 - 1;
    int yy = y + dy, xx = x + dx;
    float hv = ((unsigned)yy < (unsigned)H_ && (unsigned)xx < (unsigned)W_)
                   ? h3i[pb + yy * W_ + xx] : 0.f;
    float wv = b2f(w3[(size_t)(b * 8 + p) * HW + rem]);
    ws3 += wv;
    s3 += wv * hv;
  }
  s3 += (1.f - ws3) * h3i[t];
  float m3 = mask[(size_t)(b * 3 + 0) * HW + rem];
  float n3 = (1.f - m3) * s3 + m3 * h0v;
  h3o[t] = n3;

  float s5 = 0.f, ws5 = 0.f;
#pragma unroll
  for (int p = 0; p < 24; ++p) {
    int tap = (p < 12) ? p : p + 1;
    int dy = tap / 5 - 2, dx = tap % 5 - 2;
    int yy = y + dy, xx = x + dx;
    float hv = ((unsigned)yy < (unsigned)H_ && (unsigned)xx < (unsigned)W_)
                   ? h5i[pb + yy * W_ + xx] : 0.f;
    float wv = b2f(w5[(size_t)(b * 24 + p) * HW + rem]);
    ws5 += wv;
    s5 += wv * hv;
  }
  s5 += (1.f - ws5) * h5i[t];
  float m5 = mask[(size_t)(b * 3 + 1) * HW + rem];
  float n5 = (1.f - m5) * s5 + m5 * h0v;
  h5o[t] = n5;

  float s7 = 0.f, ws7 = 0.f;
#pragma unroll
  for (int p = 0; p < 48; ++p) {
    int tap = (p < 24) ? p : p + 1;
    int dy = tap / 7 - 3, dx = tap % 7 - 3;
    int yy = y + dy, xx = x + dx;
    float hv = ((unsigned)yy < (unsigned)H_ && (unsigned)xx < (unsigned)W_)
                   ? h7i[pb + yy * W_ + xx] : 0.f;
    float wv = b2f(w7[(size_t)(b * 48 + p) * HW + rem]);
    ws7 += wv;
    s7 += wv * hv;
  }
  s7 += (1.f - ws7) * h7i[t];
  float m7 = mask[(size_t)(b * 3 + 2) * HW + rem];
  float n7 = (1.f - m7) * s7 + m7 * h0v;
  h7o[t] = n7;

  if (chn >= 0) {
    float c3 = conf[(size_t)(b * 3 + 0) * HW + rem];
    float c5 = conf[(size_t)(b * 3 + 1) * HW + rem];
    float c7 = conf[(size_t)(b * 3 + 2) * HW + rem];
    hns[(size_t)(b * 3 + chn) * HW + rem] = c3 * n3 + c5 * n5 + c7 * n7;
  }
}

extern "C" void kernel_launch(void* const* d_in, const int* in_sizes, int n_in,
                              void* d_out, int out_size, void* d_ws, size_t ws_size,
                              hipStream_t stream) {
  const float* fout = (const float*)d_in[0];
  const float* hn   = (const float*)d_in[1];
  const float* h0   = (const float*)d_in[2];
  const float* k3w1 = (const float*)d_in[3];
  const float* k3s1 = (const float*)d_in[4];
  const float* k3b1 = (const float*)d_in[5];
  const float* k3w2 = (const float*)d_in[6];
  const float* k3s2 = (const float*)d_in[7];
  const float* k3b2 = (const float*)d_in[8];
  const float* k5w1 = (const float*)d_in[9];
  const float* k5s1 = (const float*)d_in[10];
  const float* k5b1 = (const float*)d_in[11];
  const float* k5w2 = (const float*)d_in[12];
  const float* k5s2 = (const float*)d_in[13];
  const float* k5b2 = (const float*)d_in[14];
  const float* k7w1 = (const float*)d_in[15];
  const float* k7s1 = (const float*)d_in[16];
  const float* k7b1 = (const float*)d_in[17];
  const float* k7w2 = (const float*)d_in[18];
  const float* k7s2 = (const float*)d_in[19];
  const float* k7b2 = (const float*)d_in[20];
  const float* mw1  = (const float*)d_in[21];
  const float* ms1  = (const float*)d_in[22];
  const float* mb1  = (const float*)d_in[23];
  const float* mw2  = (const float*)d_in[24];
  const float* mbias2 = (const float*)d_in[25];
  const float* cw1  = (const float*)d_in[26];
  const float* cs1  = (const float*)d_in[27];
  const float* cb1  = (const float*)d_in[28];
  const float* cw2  = (const float*)d_in[29];
  const float* cbias2 = (const float*)d_in[30];
  const float* tw1  = (const float*)d_in[31];
  const float* ts1  = (const float*)d_in[32];
  const float* tb1  = (const float*)d_in[33];
  const float* tw2  = (const float*)d_in[34];
  const float* tbias2 = (const float*)d_in[35];

  float* out = (float*)d_out;

  // workspace: bf16 h(32)+w(80) = 224 B/px; fp32 mask/conf/hA/hns = 60 B/px
  // total 284 B/px ~= 177 MB (proven-safe)
  if (ws_size < (size_t)NP * 284) return;
  ushort* h    = (ushort*)d_ws;            // 32*NP bf16 NHWC
  ushort* w3   = h    + (size_t)32 * NP;   // 8*NP  bf16 NCHW (no mid)
  ushort* w5   = w3   + (size_t)8 * NP;    // 24*NP
  ushort* w7   = w5   + (size_t)24 * NP;   // 48*NP
  float* mask  = (float*)(w7 + (size_t)48 * NP);  // 3*NP f32
  float* conf  = mask + (size_t)3 * NP;    // 3*NP f32
  float* hA    = conf + (size_t)3 * NP;    // 6*NP f32 ping-pong
  float* hns   = hA   + (size_t)6 * NP;    // 3*NP f32

  dim3 blk(256);
  dim3 gc(W_ / 64, H_ / 4, B_);   // 19 x 64 x 2
  int ge = NP / 256;

  // kernel-generator branches: split-precision conv1 + conv2
  convs1<<<gc, blk, 0, stream>>>(fout, k3w1, k3s1, k3b1, h);
  convs2<1, 4><<<gc, blk, 0, stream>>>(h, k3w2, k3s2, k3b2, w3, 8);
  convs1<<<gc, blk, 0, stream>>>(fout, k5w1, k5s1, k5b1, h);
  convs2<2, 3><<<gc, blk, 0, stream>>>(h, k5w2, k5s2, k5b2, w5, 24);
  convs1<<<gc, blk, 0, stream>>>(fout, k7w1, k7s1, k7b1, h);
  convs2<3, 2><<<gc, blk, 0, stream>>>(h, k7w2, k7s2, k7b2, w7, 48);

  // mask branch (plain bf16)
  convmf<2, 0, 0, 1, 3><<<gc, blk, 0, stream>>>(fout, nullptr, nullptr, mw1, ms1, mb1, nullptr, h, nullptr, 32);
  convmf<1, 2, 0, 0, 4><<<gc, blk, 0, stream>>>(nullptr, h, nullptr, mw2, nullptr, mbias2, h0, nullptr, mask, 3);

  // confidence branch (plain bf16)
  convmf<2, 0, 0, 1, 3><<<gc, blk, 0, stream>>>(fout, nullptr, nullptr, cw1, cs1, cb1, nullptr, h, nullptr, 32);
  convmf<1, 3, 0, 0, 4><<<gc, blk, 0, stream>>>(nullptr, h, nullptr, cw2, nullptr, cbias2, nullptr, nullptr, conf, 3);

  // propagation
  float* h3c = hA + (size_t)0 * NP; float* h3n = hA + (size_t)1 * NP;
  float* h5c = hA + (size_t)2 * NP; float* h5n = hA + (size_t)3 * NP;
  float* h7c = hA + (size_t)4 * NP; float* h7n = hA + (size_t)5 * NP;

  init_k<<<ge, blk, 0, stream>>>(hn, h3c, h5c, h7c, hns);
  for (int i = 0; i < 6; ++i) {
    int chn = (i == 2) ? 1 : ((i == 5) ? 2 : -1);
    iterate_k<<<ge, blk, 0, stream>>>(h3c, h5c, h7c, h3n, h5n, h7n,
                                      w3, w5, w7, mask, h0, hns, chn, conf);
    float* t;
    t = h3c; h3c = h3n; h3n = t;
    t = h5c; h5c = h5n; h5n = t;
    t = h7c; h7c = h7n; h7n = t;
  }

  // final temporal-weight branch (plain bf16; hns via KB2 hi/lo path)
  convmf<2, 0, 1, 1, 2><<<gc, blk, 0, stream>>>(fout, nullptr, hns, tw1, ts1, tb1, nullptr, h, nullptr, 32);
  convmf<1, 4, 0, 0, 4><<<gc, blk, 0, stream>>>(nullptr, h, hns, tw2, nullptr, tbias2, nullptr, nullptr, out, 3);
}

// Round 7
// 1124.032 us; speedup vs baseline: 2.6562x; 1.0674x over previous
//
#include <hip/hip_runtime.h>
#include <hip/hip_bf16.h>

constexpr int B_ = 2, H_ = 256, W_ = 1216;
constexpr int HW = H_ * W_;          // 311296
constexpr int NP = B_ * HW;          // 622592
constexpr float EPS_ = 1e-6f;

typedef __bf16 bfrag __attribute__((ext_vector_type(8)));
typedef float f4 __attribute__((ext_vector_type(4)));

union BU { uint4 u; bfrag f; };

__device__ __forceinline__ ushort f2b(float x) {
  uint u = __float_as_uint(x);
  u += 0x7fffu + ((u >> 16) & 1u);
  return (ushort)(u >> 16);
}
__device__ __forceinline__ float b2f(ushort u) {
  return __uint_as_float(((uint)u) << 16);
}

// ---------------------------------------------------------------------------
// Split-precision conv1 for the w-chains: fout(fp32 NCHW) -> h(bf16 NHWC).
// fp32-grade via hi/lo bf16: acc = Whi*Xhi + Whi*Xlo + Wlo*Xhi (3 MFMA/tap).
// 256 threads = 4 waves. ILP restructure (R7): tap outer, all 4 t-groups
// unrolled inner -> 8 independent MFMA chains/wave, loads shared per tap.
// Per-chain accumulation order identical to R5 (tap-major) -> bitwise-same.
// ---------------------------------------------------------------------------
__global__ __launch_bounds__(256, 2)
void convs1(const float* __restrict__ xf, const float* __restrict__ wg,
            const float* __restrict__ scale, const float* __restrict__ bias,
            ushort* __restrict__ outh)
{
  __shared__ ushort buf[25344];   // max(wl 18432, xl 25344) ushorts = 50.7 KB

  const int tid = threadIdx.x;
  const int lane = tid & 63;
  const int wid = tid >> 6;
  const int x0 = blockIdx.x * 64, y0 = blockIdx.y * 4, b = blockIdx.z;

  // phase A: weights OIHW fp32 -> [tap][co][ci] hi (buf[0..9216)) / lo (+9216)
  for (int i = tid; i < 9 * 32 * 32; i += 256) {
    int ci = i & 31, rest = i >> 5;
    int co = rest & 31, tap = rest >> 5;
    float v = wg[(co * 32 + ci) * 9 + tap];
    ushort hi = f2b(v);
    ushort lo = f2b(v - b2f(hi));
    int idx = (tap * 32 + co) * 32 + ci;
    buf[idx] = hi;
    buf[9216 + idx] = lo;
  }
  __syncthreads();

  bfrag avhi[2][9], avlo[2][9];
#pragma unroll
  for (int tap = 0; tap < 9; ++tap)
#pragma unroll
    for (int mt = 0; mt < 2; ++mt) {
      int idx = ((tap * 32) + mt * 16 + (lane & 15)) * 32 + (lane >> 4) * 8;
      avhi[mt][tap] = *(const bfrag*)&buf[idx];
      avlo[mt][tap] = *(const bfrag*)&buf[9216 + idx];
    }
  __syncthreads();

  // phase B: input tile rows y0-1..y0+4, cols x0-1..x0+64, hi at [0..12672),
  // lo at [12672..25344), layout [pix][ci]
  for (int i = tid; i < 396 * 4; i += 256) {
    int oct = i & 3, rest = i >> 2;
    int xx = rest % 66, rr = rest / 66;
    int yy = y0 - 1 + rr, x = x0 - 1 + xx;
    uint4 vh = {0, 0, 0, 0}, vl = {0, 0, 0, 0};
    if ((unsigned)yy < (unsigned)H_ && (unsigned)x < (unsigned)W_) {
      const float* src = xf + ((size_t)b * 32 + oct * 8) * HW + (size_t)yy * W_ + x;
      uint uh[4], ul[4];
#pragma unroll
      for (int j = 0; j < 4; ++j) {
        float a = src[(size_t)(2 * j + 0) * HW];
        float c = src[(size_t)(2 * j + 1) * HW];
        ushort ah = f2b(a), ch = f2b(c);
        ushort al = f2b(a - b2f(ah)), cl = f2b(c - b2f(ch));
        uh[j] = (uint)ah | ((uint)ch << 16);
        ul[j] = (uint)al | ((uint)cl << 16);
      }
      vh = uint4{uh[0], uh[1], uh[2], uh[3]};
      vl = uint4{ul[0], ul[1], ul[2], ul[3]};
    }
    *(uint4*)&buf[rest * 32 + oct * 8] = vh;
    *(uint4*)&buf[12672 + rest * 32 + oct * 8] = vl;
  }
  __syncthreads();

  const int n = lane & 15, quad = lane >> 4;

  f4 acc[4][2];
#pragma unroll
  for (int tu = 0; tu < 4; ++tu)
#pragma unroll
    for (int mt = 0; mt < 2; ++mt) acc[tu][mt] = f4{0.f, 0.f, 0.f, 0.f};

#pragma unroll
  for (int tap = 0; tap < 9; ++tap) {
    int dy = tap / 3, dx = tap % 3;
#pragma unroll
    for (int tu = 0; tu < 4; ++tu) {
      int t = wid + tu * 4;
      int r = t >> 2, g = t & 3;
      int pix = (r + dy) * 66 + g * 16 + n + dx;
      bfrag bhi = *(const bfrag*)&buf[pix * 32 + quad * 8];
      bfrag blo = *(const bfrag*)&buf[12672 + pix * 32 + quad * 8];
#pragma unroll
      for (int mt = 0; mt < 2; ++mt) {
        acc[tu][mt] = __builtin_amdgcn_mfma_f32_16x16x32_bf16(avhi[mt][tap], bhi, acc[tu][mt], 0, 0, 0);
        acc[tu][mt] = __builtin_amdgcn_mfma_f32_16x16x32_bf16(avhi[mt][tap], blo, acc[tu][mt], 0, 0, 0);
        acc[tu][mt] = __builtin_amdgcn_mfma_f32_16x16x32_bf16(avlo[mt][tap], bhi, acc[tu][mt], 0, 0, 0);
      }
    }
  }

#pragma unroll
  for (int tu = 0; tu < 4; ++tu) {
    int t = wid + tu * 4;
    int r = t >> 2, g = t & 3;
    int gx = x0 + g * 16 + n, gy = y0 + r;
    size_t bpix = (size_t)b * HW + (size_t)gy * W_ + gx;
#pragma unroll
    for (int mt = 0; mt < 2; ++mt) {
      int cob = mt * 16 + quad * 4;
      float v0 = fmaxf(acc[tu][mt][0] * scale[cob + 0] + bias[cob + 0], 0.f);
      float v1 = fmaxf(acc[tu][mt][1] * scale[cob + 1] + bias[cob + 1], 0.f);
      float v2 = fmaxf(acc[tu][mt][2] * scale[cob + 2] + bias[cob + 2], 0.f);
      float v3 = fmaxf(acc[tu][mt][3] * scale[cob + 3] + bias[cob + 3], 0.f);
      uint u0 = (uint)f2b(v0) | ((uint)f2b(v1) << 16);
      uint u1 = (uint)f2b(v2) | ((uint)f2b(v3) << 16);
      *(uint2*)&outh[bpix * 32 + cob] = uint2{u0, u1};
    }
  }
}

// ---------------------------------------------------------------------------
// Split-precision conv2 for the w-chains: h(bf16 NHWC, EXACT) -> w planes.
// Input exact => only weight split: acc = Whi*X + Wlo*X (2 MFMA/tap).
// ILP restructure (R7): tap outer, alo loaded once per tap (t-invariant,
// was re-loaded 4x in R5), 4 t-groups unrolled -> 4*nM independent chains.
// LDS: [wl_lo | union(wl_hi, xl)]; Ahi in regs. Epilogue: normalize, no mid.
// ---------------------------------------------------------------------------
template<int nM, int MINW>
__global__ __launch_bounds__(256, MINW)
void convs2(const ushort* __restrict__ xh, const float* __restrict__ wg,
            const float* __restrict__ scale, const float* __restrict__ bias,
            ushort* __restrict__ outw, int CO)
{
  constexpr int NM16 = nM * 16;
  constexpr int WSZ = 9 * NM16 * 32;
  constexpr int R2 = (WSZ > 12672) ? WSZ : 12672;
  __shared__ ushort buf[WSZ + R2];   // nM=3: 55.3 KB

  const int tid = threadIdx.x;
  const int lane = tid & 63;
  const int wid = tid >> 6;
  const int x0 = blockIdx.x * 64, y0 = blockIdx.y * 4, b = blockIdx.z;

  // phase A: weights -> lo at buf[0..WSZ), hi at buf[WSZ..WSZ+WSZ)
  for (int i = tid; i < WSZ; i += 256) {
    int ci = i & 31, rest = i >> 5;
    int co = rest % NM16, tap = rest / NM16;
    float v = (co < CO) ? wg[(co * 32 + ci) * 9 + tap] : 0.f;
    ushort hi = f2b(v);
    ushort lo = f2b(v - b2f(hi));
    buf[i] = lo;
    buf[WSZ + i] = hi;
  }
  __syncthreads();

  bfrag avhi[nM][9];
#pragma unroll
  for (int tap = 0; tap < 9; ++tap)
#pragma unroll
    for (int mt = 0; mt < nM; ++mt)
      avhi[mt][tap] = *(const bfrag*)&buf[WSZ + ((tap * NM16) + mt * 16 + (lane & 15)) * 32 + (lane >> 4) * 8];
  __syncthreads();

  // phase B: input tile (bf16 NHWC) into buf[WSZ..WSZ+12672)
  for (int i = tid; i < 396 * 4; i += 256) {
    int oct = i & 3, rest = i >> 2;
    int xx = rest % 66, rr = rest / 66;
    int yy = y0 - 1 + rr, x = x0 - 1 + xx;
    uint4 v = {0, 0, 0, 0};
    if ((unsigned)yy < (unsigned)H_ && (unsigned)x < (unsigned)W_)
      v = *(const uint4*)&xh[((size_t)b * HW + (size_t)yy * W_ + x) * 32 + oct * 8];
    *(uint4*)&buf[WSZ + rest * 32 + oct * 8] = v;
  }
  __syncthreads();

  const int n = lane & 15, quad = lane >> 4;

  f4 acc[4][nM];
#pragma unroll
  for (int tu = 0; tu < 4; ++tu)
#pragma unroll
    for (int mt = 0; mt < nM; ++mt) acc[tu][mt] = f4{0.f, 0.f, 0.f, 0.f};

#pragma unroll
  for (int tap = 0; tap < 9; ++tap) {
    int dy = tap / 3, dx = tap % 3;
    bfrag alo[nM];
#pragma unroll
    for (int mt = 0; mt < nM; ++mt)
      alo[mt] = *(const bfrag*)&buf[((tap * NM16) + mt * 16 + (lane & 15)) * 32 + (lane >> 4) * 8];
#pragma unroll
    for (int tu = 0; tu < 4; ++tu) {
      int t = wid + tu * 4;
      int r = t >> 2, g = t & 3;
      int pix = (r + dy) * 66 + g * 16 + n + dx;
      bfrag bv = *(const bfrag*)&buf[WSZ + pix * 32 + quad * 8];
#pragma unroll
      for (int mt = 0; mt < nM; ++mt) {
        acc[tu][mt] = __builtin_amdgcn_mfma_f32_16x16x32_bf16(avhi[mt][tap], bv, acc[tu][mt], 0, 0, 0);
        acc[tu][mt] = __builtin_amdgcn_mfma_f32_16x16x32_bf16(alo[mt], bv, acc[tu][mt], 0, 0, 0);
      }
    }
  }

#pragma unroll
  for (int tu = 0; tu < 4; ++tu) {
    int t = wid + tu * 4;
    int r = t >> 2, g = t & 3;
    int gx = x0 + g * 16 + n, gy = y0 + r;
    size_t gpix = (size_t)gy * W_ + gx;

    // gen-kernel normalize epilogue (mid not stored)
    float vs[nM][4];
    float pa = 0.f;
#pragma unroll
    for (int mt = 0; mt < nM; ++mt)
#pragma unroll
      for (int rg = 0; rg < 4; ++rg) {
        int co = mt * 16 + quad * 4 + rg;
        float v = (co < CO) ? acc[tu][mt][rg] * scale[co] + bias[co] : 0.f;
        vs[mt][rg] = v;
        pa += fabsf(v);
      }
    pa += __shfl_xor(pa, 16);
    pa += __shfl_xor(pa, 32);
    float inv = 1.f / (pa + EPS_);
#pragma unroll
    for (int mt = 0; mt < nM; ++mt)
#pragma unroll
      for (int rg = 0; rg < 4; ++rg) {
        int co = mt * 16 + quad * 4 + rg;
        if (co < CO)
          outw[((size_t)b * CO + co) * HW + gpix] = f2b(vs[mt][rg] * inv);
      }
  }
}

// ---------------------------------------------------------------------------
// Plain bf16 MFMA conv (mask/conf/t branches). 256 threads = 4 waves.
// ILP restructure (R7): tap outer, 4 t-groups unrolled.
// EPI: 0 relu*scale+bias -> outw NHWC bf16 (h)
//      2 sigmoid(conv+bias)*(h0>.001) -> outf 3 fp32 planes (mask)
//      3 softmax3(conv+bias) -> outf 3 fp32 planes (conf)
//      4 softmax3(conv+bias) dot hns -> outf fp32 [B][HW] (final)
// KB2: extra K-block for channels 32..34 (hns fp32), hi/lo packed in K-lanes.
// ---------------------------------------------------------------------------
template<int nM, int EPI, int KB2, int NCHWIN, int MINW>
__global__ __launch_bounds__(256, MINW)
void convmf(const float* __restrict__ xf, const ushort* __restrict__ xh,
            const float* __restrict__ hnsp,
            const float* __restrict__ wg, const float* __restrict__ scale,
            const float* __restrict__ bias, const float* __restrict__ h0,
            ushort* __restrict__ outw, float* __restrict__ outf, int CO)
{
  constexpr int NM16 = nM * 16;
  constexpr int CIN = KB2 ? 35 : 32;
  __shared__ ushort wl[9 * NM16 * 32];
  __shared__ ushort xl[396 * 32];
  __shared__ ushort wl2[KB2 ? 9 * 32 * 8 : 8];
  __shared__ ushort xl2[KB2 ? 396 * 8 : 8];

  const int tid = threadIdx.x;
  const int lane = tid & 63;
  const int wid = tid >> 6;
  const int x0 = blockIdx.x * 64, y0 = blockIdx.y * 4, b = blockIdx.z;

  for (int i = tid; i < 9 * NM16 * 32; i += 256) {
    int ci = i & 31, rest = i >> 5;
    int co = rest % NM16, tap = rest / NM16;
    float v = (co < CO) ? wg[(co * CIN + ci) * 9 + tap] : 0.f;
    wl[(tap * NM16 + co) * 32 + ci] = f2b(v);
  }
  if (KB2) {
    for (int i = tid; i < 9 * 32 * 8; i += 256) {
      int c8 = i & 7, rest = i >> 3;
      int co = rest & 31, tap = rest >> 5;
      int cc = (c8 < 3) ? c8 : ((c8 < 6) ? c8 - 3 : -1);
      float v = (cc >= 0) ? wg[(co * 35 + 32 + cc) * 9 + tap] : 0.f;
      wl2[(tap * 32 + co) * 8 + c8] = f2b(v);
    }
    for (int i = tid; i < 396; i += 256) {
      int xx = i % 66, rr = i / 66;
      int yy = y0 - 1 + rr, x = x0 - 1 + xx;
      float v0 = 0.f, v1 = 0.f, v2 = 0.f;
      if ((unsigned)yy < (unsigned)H_ && (unsigned)x < (unsigned)W_) {
        size_t pix = (size_t)yy * W_ + x;
        v0 = hnsp[((size_t)b * 3 + 0) * HW + pix];
        v1 = hnsp[((size_t)b * 3 + 1) * HW + pix];
        v2 = hnsp[((size_t)b * 3 + 2) * HW + pix];
      }
      ushort h0b = f2b(v0), h1b = f2b(v1), h2b = f2b(v2);
      ushort l0 = f2b(v0 - b2f(h0b)), l1 = f2b(v1 - b2f(h1b)), l2 = f2b(v2 - b2f(h2b));
      uint u0 = (uint)h0b | ((uint)h1b << 16);
      uint u1 = (uint)h2b | ((uint)l0 << 16);
      uint u2 = (uint)l1 | ((uint)l2 << 16);
      *(uint4*)&xl2[i * 8] = uint4{u0, u1, u2, 0};
    }
  }
  if (NCHWIN) {
    for (int i = tid; i < 396 * 4; i += 256) {
      int oct = i & 3, rest = i >> 2;
      int xx = rest % 66, rr = rest / 66;
      int yy = y0 - 1 + rr, x = x0 - 1 + xx;
      uint4 v = {0, 0, 0, 0};
      if ((unsigned)yy < (unsigned)H_ && (unsigned)x < (unsigned)W_) {
        const float* src = xf + ((size_t)b * 32 + oct * 8) * HW + (size_t)yy * W_ + x;
        uint u[4];
#pragma unroll
        for (int j = 0; j < 4; ++j) {
          float a = src[(size_t)(2 * j + 0) * HW];
          float c = src[(size_t)(2 * j + 1) * HW];
          u[j] = (uint)f2b(a) | ((uint)f2b(c) << 16);
        }
        v = uint4{u[0], u[1], u[2], u[3]};
      }
      *(uint4*)&xl[rest * 32 + oct * 8] = v;
    }
  } else {
    for (int i = tid; i < 396 * 4; i += 256) {
      int oct = i & 3, rest = i >> 2;
      int xx = rest % 66, rr = rest / 66;
      int yy = y0 - 1 + rr, x = x0 - 1 + xx;
      uint4 v = {0, 0, 0, 0};
      if ((unsigned)yy < (unsigned)H_ && (unsigned)x < (unsigned)W_)
        v = *(const uint4*)&xh[((size_t)b * HW + (size_t)yy * W_ + x) * 32 + oct * 8];
      *(uint4*)&xl[rest * 32 + oct * 8] = v;
    }
  }
  __syncthreads();

  bfrag av[nM][9];
#pragma unroll
  for (int tap = 0; tap < 9; ++tap)
#pragma unroll
    for (int mt = 0; mt < nM; ++mt)
      av[mt][tap] = *(const bfrag*)&wl[((tap * NM16) + mt * 16 + (lane & 15)) * 32 + (lane >> 4) * 8];
  bfrag a2[KB2 ? nM : 1][KB2 ? 9 : 1];
  if (KB2) {
#pragma unroll
    for (int tap = 0; tap < 9; ++tap)
#pragma unroll
      for (int mt = 0; mt < nM; ++mt) {
        BU t; t.u = uint4{0, 0, 0, 0};
        if (lane < 16) t.f = *(const bfrag*)&wl2[(tap * 32 + mt * 16 + lane) * 8];
        a2[mt][tap] = t.f;
      }
  }

  const int n = lane & 15, quad = lane >> 4;

  f4 acc[4][nM];
#pragma unroll
  for (int tu = 0; tu < 4; ++tu)
#pragma unroll
    for (int mt = 0; mt < nM; ++mt) acc[tu][mt] = f4{0.f, 0.f, 0.f, 0.f};

#pragma unroll
  for (int tap = 0; tap < 9; ++tap) {
    int dy = tap / 3, dx = tap % 3;
#pragma unroll
    for (int tu = 0; tu < 4; ++tu) {
      int t = wid + tu * 4;
      int r = t >> 2, g = t & 3;
      int pix = (r + dy) * 66 + g * 16 + n + dx;
      bfrag bv = *(const bfrag*)&xl[pix * 32 + quad * 8];
#pragma unroll
      for (int mt = 0; mt < nM; ++mt)
        acc[tu][mt] = __builtin_amdgcn_mfma_f32_16x16x32_bf16(av[mt][tap], bv, acc[tu][mt], 0, 0, 0);
      if (KB2) {
        BU t2; t2.u = uint4{0, 0, 0, 0};
        if (lane < 16) t2.f = *(const bfrag*)&xl2[pix * 8];
#pragma unroll
        for (int mt = 0; mt < nM; ++mt)
          acc[tu][mt] = __builtin_amdgcn_mfma_f32_16x16x32_bf16(a2[mt][tap], t2.f, acc[tu][mt], 0, 0, 0);
      }
    }
  }

#pragma unroll
  for (int tu = 0; tu < 4; ++tu) {
    int t = wid + tu * 4;
    int r = t >> 2, g = t & 3;
    int gx = x0 + g * 16 + n, gy = y0 + r;
    size_t gpix = (size_t)gy * W_ + gx;
    size_t bpix = (size_t)b * HW + gpix;

    if constexpr (EPI == 0) {
#pragma unroll
      for (int mt = 0; mt < nM; ++mt) {
        int cob = mt * 16 + quad * 4;
        float v0 = fmaxf(acc[tu][mt][0] * scale[cob + 0] + bias[cob + 0], 0.f);
        float v1 = fmaxf(acc[tu][mt][1] * scale[cob + 1] + bias[cob + 1], 0.f);
        float v2 = fmaxf(acc[tu][mt][2] * scale[cob + 2] + bias[cob + 2], 0.f);
        float v3 = fmaxf(acc[tu][mt][3] * scale[cob + 3] + bias[cob + 3], 0.f);
        uint u0 = (uint)f2b(v0) | ((uint)f2b(v1) << 16);
        uint u1 = (uint)f2b(v2) | ((uint)f2b(v3) << 16);
        *(uint2*)&outw[bpix * 32 + cob] = uint2{u0, u1};
      }
    } else if constexpr (EPI == 2) {
      if (lane < 16) {
        float valid = (h0[bpix] > 0.001f) ? 1.f : 0.f;
#pragma unroll
        for (int rg = 0; rg < 3; ++rg) {
          float v = acc[tu][0][rg] + bias[rg];
          float sg = 1.f / (1.f + expf(-v));
          outf[((size_t)b * 3 + rg) * HW + gpix] = sg * valid;
        }
      }
    } else if constexpr (EPI == 3) {
      if (lane < 16) {
        float v0 = acc[tu][0][0] + bias[0];
        float v1 = acc[tu][0][1] + bias[1];
        float v2 = acc[tu][0][2] + bias[2];
        float m = fmaxf(v0, fmaxf(v1, v2));
        float e0 = expf(v0 - m), e1 = expf(v1 - m), e2 = expf(v2 - m);
        float inv = 1.f / (e0 + e1 + e2);
        outf[((size_t)b * 3 + 0) * HW + gpix] = e0 * inv;
        outf[((size_t)b * 3 + 1) * HW + gpix] = e1 * inv;
        outf[((size_t)b * 3 + 2) * HW + gpix] = e2 * inv;
      }
    } else if constexpr (EPI == 4) {
      if (lane < 16) {
        float v0 = acc[tu][0][0] + bias[0];
        float v1 = acc[tu][0][1] + bias[1];
        float v2 = acc[tu][0][2] + bias[2];
        float m = fmaxf(v0, fmaxf(v1, v2));
        float e0 = expf(v0 - m), e1 = expf(v1 - m), e2 = expf(v2 - m);
        float inv = 1.f / (e0 + e1 + e2);
        float a0 = hnsp[((size_t)b * 3 + 0) * HW + gpix];
        float a1 = hnsp[((size_t)b * 3 + 1) * HW + gpix];
        float a2v = hnsp[((size_t)b * 3 + 2) * HW + gpix];
        outf[bpix] = (e0 * a0 + e1 * a1 + e2 * a2v) * inv;
      }
    }
  }
}

// ---------------------------------------------------------------------------
__global__ __launch_bounds__(256)
void init_k(const float* __restrict__ hn, float* __restrict__ h3,
            float* __restrict__ h5, float* __restrict__ h7,
            float* __restrict__ hns)
{
  int t = blockIdx.x * 256 + threadIdx.x;
  if (t >= NP) return;
  float v = hn[t];
  h3[t] = v; h5[t] = v; h7[t] = v;
  int b = t / HW, rem = t - b * HW;
  hns[(size_t)b * 3 * HW + rem] = v;
}

// ---------------------------------------------------------------------------
// Propagation step. w planes bf16 w/o mid; mid = 1 - sum (fp32 recompute).
// State fp32 (values reach ~200; bf16 state was the R3 failure).
// ---------------------------------------------------------------------------
__global__ __launch_bounds__(256)
void iterate_k(const float* __restrict__ h3i, const float* __restrict__ h5i,
               const float* __restrict__ h7i,
               float* __restrict__ h3o, float* __restrict__ h5o,
               float* __restrict__ h7o,
               const ushort* __restrict__ w3, const ushort* __restrict__ w5,
               const ushort* __restrict__ w7,
               const float* __restrict__ mask, const float* __restrict__ h0,
               float* __restrict__ hns, int chn, const float* __restrict__ conf)
{
  int t = blockIdx.x * 256 + threadIdx.x;
  if (t >= NP) return;
  int b = t / HW;
  int rem = t - b * HW;
  int y = rem / W_;
  int x = rem - y * W_;
  size_t pb = (size_t)b * HW;

  float h0v = h0[t];

  float s3 = 0.f, ws3 = 0.f;
#pragma unroll
  for (int p = 0; p < 8; ++p) {
    int tap = (p < 4) ? p : p + 1;
    int dy = tap / 3 - 1, dx = tap % 3 - 1;
    int yy = y + dy, xx = x + dx;
    float hv = ((unsigned)yy < (unsigned)H_ && (unsigned)xx < (unsigned)W_)
                   ? h3i[pb + yy * W_ + xx] : 0.f;
    float wv = b2f(w3[(size_t)(b * 8 + p) * HW + rem]);
    ws3 += wv;
    s3 += wv * hv;
  }
  s3 += (1.f - ws3) * h3i[t];
  float m3 = mask[(size_t)(b * 3 + 0) * HW + rem];
  float n3 = (1.f - m3) * s3 + m3 * h0v;
  h3o[t] = n3;

  float s5 = 0.f, ws5 = 0.f;
#pragma unroll
  for (int p = 0; p < 24; ++p) {
    int tap = (p < 12) ? p : p + 1;
    int dy = tap / 5 - 2, dx = tap % 5 - 2;
    int yy = y + dy, xx = x + dx;
    float hv = ((unsigned)yy < (unsigned)H_ && (unsigned)xx < (unsigned)W_)
                   ? h5i[pb + yy * W_ + xx] : 0.f;
    float wv = b2f(w5[(size_t)(b * 24 + p) * HW + rem]);
    ws5 += wv;
    s5 += wv * hv;
  }
  s5 += (1.f - ws5) * h5i[t];
  float m5 = mask[(size_t)(b * 3 + 1) * HW + rem];
  float n5 = (1.f - m5) * s5 + m5 * h0v;
  h5o[t] = n5;

  float s7 = 0.f, ws7 = 0.f;
#pragma unroll
  for (int p = 0; p < 48; ++p) {
    int tap = (p < 24) ? p : p + 1;
    int dy = tap / 7 - 3, dx = tap % 7 - 3;
    int yy = y + dy, xx = x + dx;
    float hv = ((unsigned)yy < (unsigned)H_ && (unsigned)xx < (unsigned)W_)
                   ? h7i[pb + yy * W_ + xx] : 0.f;
    float wv = b2f(w7[(size_t)(b * 48 + p) * HW + rem]);
    ws7 += wv;
    s7 += wv * hv;
  }
  s7 += (1.f - ws7) * h7i[t];
  float m7 = mask[(size_t)(b * 3 + 2) * HW + rem];
  float n7 = (1.f - m7) * s7 + m7 * h0v;
  h7o[t] = n7;

  if (chn >= 0) {
    float c3 = conf[(size_t)(b * 3 + 0) * HW + rem];
    float c5 = conf[(size_t)(b * 3 + 1) * HW + rem];
    float c7 = conf[(size_t)(b * 3 + 2) * HW + rem];
    hns[(size_t)(b * 3 + chn) * HW + rem] = c3 * n3 + c5 * n5 + c7 * n7;
  }
}

extern "C" void kernel_launch(void* const* d_in, const int* in_sizes, int n_in,
                              void* d_out, int out_size, void* d_ws, size_t ws_size,
                              hipStream_t stream) {
  const float* fout = (const float*)d_in[0];
  const float* hn   = (const float*)d_in[1];
  const float* h0   = (const float*)d_in[2];
  const float* k3w1 = (const float*)d_in[3];
  const float* k3s1 = (const float*)d_in[4];
  const float* k3b1 = (const float*)d_in[5];
  const float* k3w2 = (const float*)d_in[6];
  const float* k3s2 = (const float*)d_in[7];
  const float* k3b2 = (const float*)d_in[8];
  const float* k5w1 = (const float*)d_in[9];
  const float* k5s1 = (const float*)d_in[10];
  const float* k5b1 = (const float*)d_in[11];
  const float* k5w2 = (const float*)d_in[12];
  const float* k5s2 = (const float*)d_in[13];
  const float* k5b2 = (const float*)d_in[14];
  const float* k7w1 = (const float*)d_in[15];
  const float* k7s1 = (const float*)d_in[16];
  const float* k7b1 = (const float*)d_in[17];
  const float* k7w2 = (const float*)d_in[18];
  const float* k7s2 = (const float*)d_in[19];
  const float* k7b2 = (const float*)d_in[20];
  const float* mw1  = (const float*)d_in[21];
  const float* ms1  = (const float*)d_in[22];
  const float* mb1  = (const float*)d_in[23];
  const float* mw2  = (const float*)d_in[24];
  const float* mbias2 = (const float*)d_in[25];
  const float* cw1  = (const float*)d_in[26];
  const float* cs1  = (const float*)d_in[27];
  const float* cb1  = (const float*)d_in[28];
  const float* cw2  = (const float*)d_in[29];
  const float* cbias2 = (const float*)d_in[30];
  const float* tw1  = (const float*)d_in[31];
  const float* ts1  = (const float*)d_in[32];
  const float* tb1  = (const float*)d_in[33];
  const float* tw2  = (const float*)d_in[34];
  const float* tbias2 = (const float*)d_in[35];

  float* out = (float*)d_out;

  // workspace: bf16 h(32)+w(80) = 224 B/px; fp32 mask/conf/hA/hns = 60 B/px
  // total 284 B/px ~= 177 MB (proven-safe)
  if (ws_size < (size_t)NP * 284) return;
  ushort* h    = (ushort*)d_ws;            // 32*NP bf16 NHWC
  ushort* w3   = h    + (size_t)32 * NP;   // 8*NP  bf16 NCHW (no mid)
  ushort* w5   = w3   + (size_t)8 * NP;    // 24*NP
  ushort* w7   = w5   + (size_t)24 * NP;   // 48*NP
  float* mask  = (float*)(w7 + (size_t)48 * NP);  // 3*NP f32
  float* conf  = mask + (size_t)3 * NP;    // 3*NP f32
  float* hA    = conf + (size_t)3 * NP;    // 6*NP f32 ping-pong
  float* hns   = hA   + (size_t)6 * NP;    // 3*NP f32

  dim3 blk(256);
  dim3 gc(W_ / 64, H_ / 4, B_);   // 19 x 64 x 2
  int ge = NP / 256;

  // kernel-generator branches: split-precision conv1 + conv2
  convs1<<<gc, blk, 0, stream>>>(fout, k3w1, k3s1, k3b1, h);
  convs2<1, 4><<<gc, blk, 0, stream>>>(h, k3w2, k3s2, k3b2, w3, 8);
  convs1<<<gc, blk, 0, stream>>>(fout, k5w1, k5s1, k5b1, h);
  convs2<2, 3><<<gc, blk, 0, stream>>>(h, k5w2, k5s2, k5b2, w5, 24);
  convs1<<<gc, blk, 0, stream>>>(fout, k7w1, k7s1, k7b1, h);
  convs2<3, 2><<<gc, blk, 0, stream>>>(h, k7w2, k7s2, k7b2, w7, 48);

  // mask branch (plain bf16)
  convmf<2, 0, 0, 1, 3><<<gc, blk, 0, stream>>>(fout, nullptr, nullptr, mw1, ms1, mb1, nullptr, h, nullptr, 32);
  convmf<1, 2, 0, 0, 4><<<gc, blk, 0, stream>>>(nullptr, h, nullptr, mw2, nullptr, mbias2, h0, nullptr, mask, 3);

  // confidence branch (plain bf16)
  convmf<2, 0, 0, 1, 3><<<gc, blk, 0, stream>>>(fout, nullptr, nullptr, cw1, cs1, cb1, nullptr, h, nullptr, 32);
  convmf<1, 3, 0, 0, 4><<<gc, blk, 0, stream>>>(nullptr, h, nullptr, cw2, nullptr, cbias2, nullptr, nullptr, conf, 3);

  // propagation
  float* h3c = hA + (size_t)0 * NP; float* h3n = hA + (size_t)1 * NP;
  float* h5c = hA + (size_t)2 * NP; float* h5n = hA + (size_t)3 * NP;
  float* h7c = hA + (size_t)4 * NP; float* h7n = hA + (size_t)5 * NP;

  init_k<<<ge, blk, 0, stream>>>(hn, h3c, h5c, h7c, hns);
  for (int i = 0; i < 6; ++i) {
    int chn = (i == 2) ? 1 : ((i == 5) ? 2 : -1);
    iterate_k<<<ge, blk, 0, stream>>>(h3c, h5c, h7c, h3n, h5n, h7n,
                                      w3, w5, w7, mask, h0, hns, chn, conf);
    float* t;
    t = h3c; h3c = h3n; h3n = t;
    t = h5c; h5c = h5n; h5n = t;
    t = h7c; h7c = h7n; h7n = t;
  }

  // final temporal-weight branch (plain bf16; hns via KB2 hi/lo path)
  convmf<2, 0, 1, 1, 2><<<gc, blk, 0, stream>>>(fout, nullptr, hns, tw1, ts1, tb1, nullptr, h, nullptr, 32);
  convmf<1, 4, 0, 0, 4><<<gc, blk, 0, stream>>>(nullptr, h, hns, tw2, nullptr, tbias2, nullptr, nullptr, out, 3);
}

// Round 8
// 1041.152 us; speedup vs baseline: 2.8677x; 1.0796x over previous
//
#include <hip/hip_runtime.h>
#include <hip/hip_bf16.h>

constexpr int B_ = 2, H_ = 256, W_ = 1216;
constexpr int HW = H_ * W_;          // 311296
constexpr int NP = B_ * HW;          // 622592
constexpr int WP = W_ + 2;           // 1218 padded width
constexpr int HP = H_ + 2;           // 258  padded height
constexpr int HWP = HP * WP;         // 314244
constexpr float EPS_ = 1e-6f;

typedef __bf16 bfrag __attribute__((ext_vector_type(8)));
typedef float f4 __attribute__((ext_vector_type(4)));

union BU { uint4 u; bfrag f; };

__device__ __forceinline__ ushort f2b(float x) {
  uint u = __float_as_uint(x);
  u += 0x7fffu + ((u >> 16) & 1u);
  return (ushort)(u >> 16);
}
__device__ __forceinline__ float b2f(ushort u) {
  return __uint_as_float(((uint)u) << 16);
}

// ---------------------------------------------------------------------------
// Zero the pad ring of hP (padded NHWC bf16 [b][HP][WP][32]).
// Interior is overwritten by every conv1; ring must be zero so conv2-family
// kernels can load B unconditionally. Runs once per kernel_launch (ws is
// re-poisoned before every call).
// ---------------------------------------------------------------------------
__global__ __launch_bounds__(256)
void zring_k(ushort* __restrict__ hP) {
  constexpr int PB = 2 * WP * 4 + 2 * (HP - 2) * 4;   // uint4 units per batch
  int i = blockIdx.x * 256 + threadIdx.x;
  if (i >= 2 * PB) return;
  int b = i / PB, r = i % PB;
  size_t idx;
  if (r < WP * 4) idx = (size_t)r;                                   // top row
  else if (r < 2 * WP * 4) idx = (size_t)(HP - 1) * WP * 4 + (r - WP * 4);  // bottom
  else {
    int q = r - 2 * WP * 4;
    int row = q >> 3, k = q & 7;
    int col = (k < 4) ? k : (WP - 1) * 4 + (k - 4);
    idx = (size_t)(row + 1) * WP * 4 + col;
  }
  *(uint4*)&hP[(size_t)b * HWP * 32 + idx * 8] = uint4{0, 0, 0, 0};
}

// ---------------------------------------------------------------------------
// Split-precision conv1 for the w-chains: fout(fp32 NCHW) -> hP(bf16 padded
// NHWC). acc = Whi*Xhi + Whi*Xlo + Wlo*Xhi (3 MFMA/tap). Unchanged from R7
// except the store goes to the padded layout.
// ---------------------------------------------------------------------------
__global__ __launch_bounds__(256, 2)
void convs1(const float* __restrict__ xf, const float* __restrict__ wg,
            const float* __restrict__ scale, const float* __restrict__ bias,
            ushort* __restrict__ outh)
{
  __shared__ ushort buf[25344];   // max(wl 18432, xl 25344) ushorts = 50.7 KB

  const int tid = threadIdx.x;
  const int lane = tid & 63;
  const int wid = tid >> 6;
  const int x0 = blockIdx.x * 64, y0 = blockIdx.y * 4, b = blockIdx.z;

  for (int i = tid; i < 9 * 32 * 32; i += 256) {
    int ci = i & 31, rest = i >> 5;
    int co = rest & 31, tap = rest >> 5;
    float v = wg[(co * 32 + ci) * 9 + tap];
    ushort hi = f2b(v);
    ushort lo = f2b(v - b2f(hi));
    int idx = (tap * 32 + co) * 32 + ci;
    buf[idx] = hi;
    buf[9216 + idx] = lo;
  }
  __syncthreads();

  bfrag avhi[2][9], avlo[2][9];
#pragma unroll
  for (int tap = 0; tap < 9; ++tap)
#pragma unroll
    for (int mt = 0; mt < 2; ++mt) {
      int idx = ((tap * 32) + mt * 16 + (lane & 15)) * 32 + (lane >> 4) * 8;
      avhi[mt][tap] = *(const bfrag*)&buf[idx];
      avlo[mt][tap] = *(const bfrag*)&buf[9216 + idx];
    }
  __syncthreads();

  for (int i = tid; i < 396 * 4; i += 256) {
    int oct = i & 3, rest = i >> 2;
    int xx = rest % 66, rr = rest / 66;
    int yy = y0 - 1 + rr, x = x0 - 1 + xx;
    uint4 vh = {0, 0, 0, 0}, vl = {0, 0, 0, 0};
    if ((unsigned)yy < (unsigned)H_ && (unsigned)x < (unsigned)W_) {
      const float* src = xf + ((size_t)b * 32 + oct * 8) * HW + (size_t)yy * W_ + x;
      uint uh[4], ul[4];
#pragma unroll
      for (int j = 0; j < 4; ++j) {
        float a = src[(size_t)(2 * j + 0) * HW];
        float c = src[(size_t)(2 * j + 1) * HW];
        ushort ah = f2b(a), ch = f2b(c);
        ushort al = f2b(a - b2f(ah)), cl = f2b(c - b2f(ch));
        uh[j] = (uint)ah | ((uint)ch << 16);
        ul[j] = (uint)al | ((uint)cl << 16);
      }
      vh = uint4{uh[0], uh[1], uh[2], uh[3]};
      vl = uint4{ul[0], ul[1], ul[2], ul[3]};
    }
    *(uint4*)&buf[rest * 32 + oct * 8] = vh;
    *(uint4*)&buf[12672 + rest * 32 + oct * 8] = vl;
  }
  __syncthreads();

  const int n = lane & 15, quad = lane >> 4;

  f4 acc[4][2];
#pragma unroll
  for (int tu = 0; tu < 4; ++tu)
#pragma unroll
    for (int mt = 0; mt < 2; ++mt) acc[tu][mt] = f4{0.f, 0.f, 0.f, 0.f};

#pragma unroll
  for (int tap = 0; tap < 9; ++tap) {
    int dy = tap / 3, dx = tap % 3;
#pragma unroll
    for (int tu = 0; tu < 4; ++tu) {
      int t = wid + tu * 4;
      int r = t >> 2, g = t & 3;
      int pix = (r + dy) * 66 + g * 16 + n + dx;
      bfrag bhi = *(const bfrag*)&buf[pix * 32 + quad * 8];
      bfrag blo = *(const bfrag*)&buf[12672 + pix * 32 + quad * 8];
#pragma unroll
      for (int mt = 0; mt < 2; ++mt) {
        acc[tu][mt] = __builtin_amdgcn_mfma_f32_16x16x32_bf16(avhi[mt][tap], bhi, acc[tu][mt], 0, 0, 0);
        acc[tu][mt] = __builtin_amdgcn_mfma_f32_16x16x32_bf16(avhi[mt][tap], blo, acc[tu][mt], 0, 0, 0);
        acc[tu][mt] = __builtin_amdgcn_mfma_f32_16x16x32_bf16(avlo[mt][tap], bhi, acc[tu][mt], 0, 0, 0);
      }
    }
  }

#pragma unroll
  for (int tu = 0; tu < 4; ++tu) {
    int t = wid + tu * 4;
    int r = t >> 2, g = t & 3;
    int gx = x0 + g * 16 + n, gy = y0 + r;
    size_t bpix = (size_t)b * HWP + (size_t)(gy + 1) * WP + (gx + 1);  // padded
#pragma unroll
    for (int mt = 0; mt < 2; ++mt) {
      int cob = mt * 16 + quad * 4;
      float v0 = fmaxf(acc[tu][mt][0] * scale[cob + 0] + bias[cob + 0], 0.f);
      float v1 = fmaxf(acc[tu][mt][1] * scale[cob + 1] + bias[cob + 1], 0.f);
      float v2 = fmaxf(acc[tu][mt][2] * scale[cob + 2] + bias[cob + 2], 0.f);
      float v3 = fmaxf(acc[tu][mt][3] * scale[cob + 3] + bias[cob + 3], 0.f);
      uint u0 = (uint)f2b(v0) | ((uint)f2b(v1) << 16);
      uint u1 = (uint)f2b(v2) | ((uint)f2b(v3) << 16);
      *(uint2*)&outh[bpix * 32 + cob] = uint2{u0, u1};
    }
  }
}

// ---------------------------------------------------------------------------
// Split-precision conv2 (R8): B loaded DIRECTLY from padded global hP —
// no input LDS staging, no second barrier, unconditional coalesced loads.
// Weights hi/lo in LDS (one barrier); Ahi cached in regs, Alo read per tap.
// acc = Whi*X + Wlo*X (input exact in bf16). Epilogue: normalize, no mid.
// ---------------------------------------------------------------------------
template<int nM, int MINW>
__global__ __launch_bounds__(256, MINW)
void convs2(const ushort* __restrict__ hP, const float* __restrict__ wg,
            const float* __restrict__ scale, const float* __restrict__ bias,
            ushort* __restrict__ outw, int CO)
{
  constexpr int NM16 = nM * 16;
  constexpr int WSZ = 9 * NM16 * 32;
  __shared__ ushort buf[2 * WSZ];   // [lo | hi]; nM=3: 55.3 KB

  const int tid = threadIdx.x;
  const int lane = tid & 63;
  const int wid = tid >> 6;
  const int x0 = blockIdx.x * 64, y0 = blockIdx.y * 4, b = blockIdx.z;

  for (int i = tid; i < WSZ; i += 256) {
    int ci = i & 31, rest = i >> 5;
    int co = rest % NM16, tap = rest / NM16;
    float v = (co < CO) ? wg[(co * 32 + ci) * 9 + tap] : 0.f;
    ushort hi = f2b(v);
    ushort lo = f2b(v - b2f(hi));
    buf[i] = lo;
    buf[WSZ + i] = hi;
  }
  __syncthreads();   // the only barrier

  bfrag avhi[nM][9];
#pragma unroll
  for (int tap = 0; tap < 9; ++tap)
#pragma unroll
    for (int mt = 0; mt < nM; ++mt)
      avhi[mt][tap] = *(const bfrag*)&buf[WSZ + ((tap * NM16) + mt * 16 + (lane & 15)) * 32 + (lane >> 4) * 8];

  const int n = lane & 15, quad = lane >> 4;
  const ushort* hb = hP + (size_t)b * HWP * 32;

  f4 acc[4][nM];
#pragma unroll
  for (int tu = 0; tu < 4; ++tu)
#pragma unroll
    for (int mt = 0; mt < nM; ++mt) acc[tu][mt] = f4{0.f, 0.f, 0.f, 0.f};

#pragma unroll
  for (int tap = 0; tap < 9; ++tap) {
    int dy = tap / 3, dx = tap % 3;
    bfrag alo[nM];
#pragma unroll
    for (int mt = 0; mt < nM; ++mt)
      alo[mt] = *(const bfrag*)&buf[((tap * NM16) + mt * 16 + (lane & 15)) * 32 + (lane >> 4) * 8];
#pragma unroll
    for (int tu = 0; tu < 4; ++tu) {
      int t = wid + tu * 4;
      int r = t >> 2, g = t & 3;
      int rb = (y0 + r + dy) * WP + x0 + g * 16 + n + dx;  // padded coords
      bfrag bv = *(const bfrag*)&hb[(size_t)rb * 32 + quad * 8];
#pragma unroll
      for (int mt = 0; mt < nM; ++mt) {
        acc[tu][mt] = __builtin_amdgcn_mfma_f32_16x16x32_bf16(avhi[mt][tap], bv, acc[tu][mt], 0, 0, 0);
        acc[tu][mt] = __builtin_amdgcn_mfma_f32_16x16x32_bf16(alo[mt], bv, acc[tu][mt], 0, 0, 0);
      }
    }
  }

#pragma unroll
  for (int tu = 0; tu < 4; ++tu) {
    int t = wid + tu * 4;
    int r = t >> 2, g = t & 3;
    int gx = x0 + g * 16 + n, gy = y0 + r;
    size_t gpix = (size_t)gy * W_ + gx;

    float vs[nM][4];
    float pa = 0.f;
#pragma unroll
    for (int mt = 0; mt < nM; ++mt)
#pragma unroll
      for (int rg = 0; rg < 4; ++rg) {
        int co = mt * 16 + quad * 4 + rg;
        float v = (co < CO) ? acc[tu][mt][rg] * scale[co] + bias[co] : 0.f;
        vs[mt][rg] = v;
        pa += fabsf(v);
      }
    pa += __shfl_xor(pa, 16);
    pa += __shfl_xor(pa, 32);
    float inv = 1.f / (pa + EPS_);
#pragma unroll
    for (int mt = 0; mt < nM; ++mt)
#pragma unroll
      for (int rg = 0; rg < 4; ++rg) {
        int co = mt * 16 + quad * 4 + rg;
        if (co < CO)
          outw[((size_t)b * CO + co) * HW + gpix] = f2b(vs[mt][rg] * inv);
      }
  }
}

// ---------------------------------------------------------------------------
// Plain bf16 conv1 for mask/conf/t branches: fout(fp32 NCHW) -> hP (padded).
// KB2: extra K-block for channels 32..34 (hns fp32), hi/lo packed in K-lanes.
// Same structure as R7 convmf EPI=0, store to padded layout.
// ---------------------------------------------------------------------------
template<int KB2, int MINW>
__global__ __launch_bounds__(256, MINW)
void conv1p(const float* __restrict__ xf, const float* __restrict__ hnsp,
            const float* __restrict__ wg, const float* __restrict__ scale,
            const float* __restrict__ bias, ushort* __restrict__ outh)
{
  constexpr int CIN = KB2 ? 35 : 32;
  __shared__ ushort wl[9 * 32 * 32];
  __shared__ ushort xl[396 * 32];
  __shared__ ushort wl2[KB2 ? 9 * 32 * 8 : 8];
  __shared__ ushort xl2[KB2 ? 396 * 8 : 8];

  const int tid = threadIdx.x;
  const int lane = tid & 63;
  const int wid = tid >> 6;
  const int x0 = blockIdx.x * 64, y0 = blockIdx.y * 4, b = blockIdx.z;

  for (int i = tid; i < 9 * 32 * 32; i += 256) {
    int ci = i & 31, rest = i >> 5;
    int co = rest & 31, tap = rest >> 5;
    float v = wg[(co * CIN + ci) * 9 + tap];
    wl[(tap * 32 + co) * 32 + ci] = f2b(v);
  }
  if (KB2) {
    for (int i = tid; i < 9 * 32 * 8; i += 256) {
      int c8 = i & 7, rest = i >> 3;
      int co = rest & 31, tap = rest >> 5;
      int cc = (c8 < 3) ? c8 : ((c8 < 6) ? c8 - 3 : -1);
      float v = (cc >= 0) ? wg[(co * 35 + 32 + cc) * 9 + tap] : 0.f;
      wl2[(tap * 32 + co) * 8 + c8] = f2b(v);
    }
    for (int i = tid; i < 396; i += 256) {
      int xx = i % 66, rr = i / 66;
      int yy = y0 - 1 + rr, x = x0 - 1 + xx;
      float v0 = 0.f, v1 = 0.f, v2 = 0.f;
      if ((unsigned)yy < (unsigned)H_ && (unsigned)x < (unsigned)W_) {
        size_t pix = (size_t)yy * W_ + x;
        v0 = hnsp[((size_t)b * 3 + 0) * HW + pix];
        v1 = hnsp[((size_t)b * 3 + 1) * HW + pix];
        v2 = hnsp[((size_t)b * 3 + 2) * HW + pix];
      }
      ushort h0b = f2b(v0), h1b = f2b(v1), h2b = f2b(v2);
      ushort l0 = f2b(v0 - b2f(h0b)), l1 = f2b(v1 - b2f(h1b)), l2 = f2b(v2 - b2f(h2b));
      uint u0 = (uint)h0b | ((uint)h1b << 16);
      uint u1 = (uint)h2b | ((uint)l0 << 16);
      uint u2 = (uint)l1 | ((uint)l2 << 16);
      *(uint4*)&xl2[i * 8] = uint4{u0, u1, u2, 0};
    }
  }
  for (int i = tid; i < 396 * 4; i += 256) {
    int oct = i & 3, rest = i >> 2;
    int xx = rest % 66, rr = rest / 66;
    int yy = y0 - 1 + rr, x = x0 - 1 + xx;
    uint4 v = {0, 0, 0, 0};
    if ((unsigned)yy < (unsigned)H_ && (unsigned)x < (unsigned)W_) {
      const float* src = xf + ((size_t)b * 32 + oct * 8) * HW + (size_t)yy * W_ + x;
      uint u[4];
#pragma unroll
      for (int j = 0; j < 4; ++j) {
        float a = src[(size_t)(2 * j + 0) * HW];
        float c = src[(size_t)(2 * j + 1) * HW];
        u[j] = (uint)f2b(a) | ((uint)f2b(c) << 16);
      }
      v = uint4{u[0], u[1], u[2], u[3]};
    }
    *(uint4*)&xl[rest * 32 + oct * 8] = v;
  }
  __syncthreads();

  bfrag av[2][9];
#pragma unroll
  for (int tap = 0; tap < 9; ++tap)
#pragma unroll
    for (int mt = 0; mt < 2; ++mt)
      av[mt][tap] = *(const bfrag*)&wl[((tap * 32) + mt * 16 + (lane & 15)) * 32 + (lane >> 4) * 8];
  bfrag a2[KB2 ? 2 : 1][KB2 ? 9 : 1];
  if (KB2) {
#pragma unroll
    for (int tap = 0; tap < 9; ++tap)
#pragma unroll
      for (int mt = 0; mt < 2; ++mt) {
        BU t; t.u = uint4{0, 0, 0, 0};
        if (lane < 16) t.f = *(const bfrag*)&wl2[(tap * 32 + mt * 16 + lane) * 8];
        a2[mt][tap] = t.f;
      }
  }

  const int n = lane & 15, quad = lane >> 4;

  f4 acc[4][2];
#pragma unroll
  for (int tu = 0; tu < 4; ++tu)
#pragma unroll
    for (int mt = 0; mt < 2; ++mt) acc[tu][mt] = f4{0.f, 0.f, 0.f, 0.f};

#pragma unroll
  for (int tap = 0; tap < 9; ++tap) {
    int dy = tap / 3, dx = tap % 3;
#pragma unroll
    for (int tu = 0; tu < 4; ++tu) {
      int t = wid + tu * 4;
      int r = t >> 2, g = t & 3;
      int pix = (r + dy) * 66 + g * 16 + n + dx;
      bfrag bv = *(const bfrag*)&xl[pix * 32 + quad * 8];
#pragma unroll
      for (int mt = 0; mt < 2; ++mt)
        acc[tu][mt] = __builtin_amdgcn_mfma_f32_16x16x32_bf16(av[mt][tap], bv, acc[tu][mt], 0, 0, 0);
      if (KB2) {
        BU t2; t2.u = uint4{0, 0, 0, 0};
        if (lane < 16) t2.f = *(const bfrag*)&xl2[pix * 8];
#pragma unroll
        for (int mt = 0; mt < 2; ++mt)
          acc[tu][mt] = __builtin_amdgcn_mfma_f32_16x16x32_bf16(a2[mt][tap], t2.f, acc[tu][mt], 0, 0, 0);
      }
    }
  }

#pragma unroll
  for (int tu = 0; tu < 4; ++tu) {
    int t = wid + tu * 4;
    int r = t >> 2, g = t & 3;
    int gx = x0 + g * 16 + n, gy = y0 + r;
    size_t bpix = (size_t)b * HWP + (size_t)(gy + 1) * WP + (gx + 1);  // padded
#pragma unroll
    for (int mt = 0; mt < 2; ++mt) {
      int cob = mt * 16 + quad * 4;
      float v0 = fmaxf(acc[tu][mt][0] * scale[cob + 0] + bias[cob + 0], 0.f);
      float v1 = fmaxf(acc[tu][mt][1] * scale[cob + 1] + bias[cob + 1], 0.f);
      float v2 = fmaxf(acc[tu][mt][2] * scale[cob + 2] + bias[cob + 2], 0.f);
      float v3 = fmaxf(acc[tu][mt][3] * scale[cob + 3] + bias[cob + 3], 0.f);
      uint u0 = (uint)f2b(v0) | ((uint)f2b(v1) << 16);
      uint u1 = (uint)f2b(v2) | ((uint)f2b(v3) << 16);
      *(uint2*)&outh[bpix * 32 + cob] = uint2{u0, u1};
    }
  }
}

// ---------------------------------------------------------------------------
// Small conv2 (CO=3) over hP, B direct from padded global; weights LDS->regs.
// EPI: 2 sigmoid(conv+bias)*(h0>.001) -> mask; 3 softmax3 -> conf;
//      4 softmax3 dot hns -> final output.
// ---------------------------------------------------------------------------
template<int EPI>
__global__ __launch_bounds__(256, 4)
void conv2g(const ushort* __restrict__ hP, const float* __restrict__ wg,
            const float* __restrict__ bias, const float* __restrict__ h0,
            const float* __restrict__ hnsp, float* __restrict__ outf)
{
  __shared__ ushort wl[9 * 16 * 32];   // 9.2 KB

  const int tid = threadIdx.x;
  const int lane = tid & 63;
  const int wid = tid >> 6;
  const int x0 = blockIdx.x * 64, y0 = blockIdx.y * 4, b = blockIdx.z;

  for (int i = tid; i < 9 * 16 * 32; i += 256) {
    int ci = i & 31, rest = i >> 5;
    int co = rest & 15, tap = rest >> 4;
    float v = (co < 3) ? wg[(co * 32 + ci) * 9 + tap] : 0.f;
    wl[(tap * 16 + co) * 32 + ci] = f2b(v);
  }
  __syncthreads();

  bfrag av[9];
#pragma unroll
  for (int tap = 0; tap < 9; ++tap)
    av[tap] = *(const bfrag*)&wl[((tap * 16) + (lane & 15)) * 32 + (lane >> 4) * 8];

  const int n = lane & 15, quad = lane >> 4;
  const ushort* hb = hP + (size_t)b * HWP * 32;

  f4 acc[4];
#pragma unroll
  for (int tu = 0; tu < 4; ++tu) acc[tu] = f4{0.f, 0.f, 0.f, 0.f};

#pragma unroll
  for (int tap = 0; tap < 9; ++tap) {
    int dy = tap / 3, dx = tap % 3;
#pragma unroll
    for (int tu = 0; tu < 4; ++tu) {
      int t = wid + tu * 4;
      int r = t >> 2, g = t & 3;
      int rb = (y0 + r + dy) * WP + x0 + g * 16 + n + dx;
      bfrag bv = *(const bfrag*)&hb[(size_t)rb * 32 + quad * 8];
      acc[tu] = __builtin_amdgcn_mfma_f32_16x16x32_bf16(av[tap], bv, acc[tu], 0, 0, 0);
    }
  }

#pragma unroll
  for (int tu = 0; tu < 4; ++tu) {
    int t = wid + tu * 4;
    int r = t >> 2, g = t & 3;
    int gx = x0 + g * 16 + n, gy = y0 + r;
    size_t gpix = (size_t)gy * W_ + gx;
    size_t bpix = (size_t)b * HW + gpix;

    if constexpr (EPI == 2) {
      if (lane < 16) {
        float valid = (h0[bpix] > 0.001f) ? 1.f : 0.f;
#pragma unroll
        for (int rg = 0; rg < 3; ++rg) {
          float v = acc[tu][rg] + bias[rg];
          float sg = 1.f / (1.f + expf(-v));
          outf[((size_t)b * 3 + rg) * HW + gpix] = sg * valid;
        }
      }
    } else if constexpr (EPI == 3) {
      if (lane < 16) {
        float v0 = acc[tu][0] + bias[0];
        float v1 = acc[tu][1] + bias[1];
        float v2 = acc[tu][2] + bias[2];
        float m = fmaxf(v0, fmaxf(v1, v2));
        float e0 = expf(v0 - m), e1 = expf(v1 - m), e2 = expf(v2 - m);
        float inv = 1.f / (e0 + e1 + e2);
        outf[((size_t)b * 3 + 0) * HW + gpix] = e0 * inv;
        outf[((size_t)b * 3 + 1) * HW + gpix] = e1 * inv;
        outf[((size_t)b * 3 + 2) * HW + gpix] = e2 * inv;
      }
    } else if constexpr (EPI == 4) {
      if (lane < 16) {
        float v0 = acc[tu][0] + bias[0];
        float v1 = acc[tu][1] + bias[1];
        float v2 = acc[tu][2] + bias[2];
        float m = fmaxf(v0, fmaxf(v1, v2));
        float e0 = expf(v0 - m), e1 = expf(v1 - m), e2 = expf(v2 - m);
        float inv = 1.f / (e0 + e1 + e2);
        float a0 = hnsp[((size_t)b * 3 + 0) * HW + gpix];
        float a1 = hnsp[((size_t)b * 3 + 1) * HW + gpix];
        float a2v = hnsp[((size_t)b * 3 + 2) * HW + gpix];
        outf[bpix] = (e0 * a0 + e1 * a1 + e2 * a2v) * inv;
      }
    }
  }
}

// ---------------------------------------------------------------------------
__global__ __launch_bounds__(256)
void init_k(const float* __restrict__ hn, float* __restrict__ h3,
            float* __restrict__ h5, float* __restrict__ h7,
            float* __restrict__ hns)
{
  int t = blockIdx.x * 256 + threadIdx.x;
  if (t >= NP) return;
  float v = hn[t];
  h3[t] = v; h5[t] = v; h7[t] = v;
  int b = t / HW, rem = t - b * HW;
  hns[(size_t)b * 3 * HW + rem] = v;
}

// ---------------------------------------------------------------------------
// Propagation step. w planes bf16 w/o mid; mid = 1 - sum (fp32 recompute).
// State fp32 (values reach ~200; bf16 state was the R3 failure).
// ---------------------------------------------------------------------------
__global__ __launch_bounds__(256)
void iterate_k(const float* __restrict__ h3i, const float* __restrict__ h5i,
               const float* __restrict__ h7i,
               float* __restrict__ h3o, float* __restrict__ h5o,
               float* __restrict__ h7o,
               const ushort* __restrict__ w3, const ushort* __restrict__ w5,
               const ushort* __restrict__ w7,
               const float* __restrict__ mask, const float* __restrict__ h0,
               float* __restrict__ hns, int chn, const float* __restrict__ conf)
{
  int t = blockIdx.x * 256 + threadIdx.x;
  if (t >= NP) return;
  int b = t / HW;
  int rem = t - b * HW;
  int y = rem / W_;
  int x = rem - y * W_;
  size_t pb = (size_t)b * HW;

  float h0v = h0[t];

  float s3 = 0.f, ws3 = 0.f;
#pragma unroll
  for (int p = 0; p < 8; ++p) {
    int tap = (p < 4) ? p : p + 1;
    int dy = tap / 3 - 1, dx = tap % 3 - 1;
    int yy = y + dy, xx = x + dx;
    float hv = ((unsigned)yy < (unsigned)H_ && (unsigned)xx < (unsigned)W_)
                   ? h3i[pb + yy * W_ + xx] : 0.f;
    float wv = b2f(w3[(size_t)(b * 8 + p) * HW + rem]);
    ws3 += wv;
    s3 += wv * hv;
  }
  s3 += (1.f - ws3) * h3i[t];
  float m3 = mask[(size_t)(b * 3 + 0) * HW + rem];
  float n3 = (1.f - m3) * s3 + m3 * h0v;
  h3o[t] = n3;

  float s5 = 0.f, ws5 = 0.f;
#pragma unroll
  for (int p = 0; p < 24; ++p) {
    int tap = (p < 12) ? p : p + 1;
    int dy = tap / 5 - 2, dx = tap % 5 - 2;
    int yy = y + dy, xx = x + dx;
    float hv = ((unsigned)yy < (unsigned)H_ && (unsigned)xx < (unsigned)W_)
                   ? h5i[pb + yy * W_ + xx] : 0.f;
    float wv = b2f(w5[(size_t)(b * 24 + p) * HW + rem]);
    ws5 += wv;
    s5 += wv * hv;
  }
  s5 += (1.f - ws5) * h5i[t];
  float m5 = mask[(size_t)(b * 3 + 1) * HW + rem];
  float n5 = (1.f - m5) * s5 + m5 * h0v;
  h5o[t] = n5;

  float s7 = 0.f, ws7 = 0.f;
#pragma unroll
  for (int p = 0; p < 48; ++p) {
    int tap = (p < 24) ? p : p + 1;
    int dy = tap / 7 - 3, dx = tap % 7 - 3;
    int yy = y + dy, xx = x + dx;
    float hv = ((unsigned)yy < (unsigned)H_ && (unsigned)xx < (unsigned)W_)
                   ? h7i[pb + yy * W_ + xx] : 0.f;
    float wv = b2f(w7[(size_t)(b * 48 + p) * HW + rem]);
    ws7 += wv;
    s7 += wv * hv;
  }
  s7 += (1.f - ws7) * h7i[t];
  float m7 = mask[(size_t)(b * 3 + 2) * HW + rem];
  float n7 = (1.f - m7) * s7 + m7 * h0v;
  h7o[t] = n7;

  if (chn >= 0) {
    float c3 = conf[(size_t)(b * 3 + 0) * HW + rem];
    float c5 = conf[(size_t)(b * 3 + 1) * HW + rem];
    float c7 = conf[(size_t)(b * 3 + 2) * HW + rem];
    hns[(size_t)(b * 3 + chn) * HW + rem] = c3 * n3 + c5 * n5 + c7 * n7;
  }
}

extern "C" void kernel_launch(void* const* d_in, const int* in_sizes, int n_in,
                              void* d_out, int out_size, void* d_ws, size_t ws_size,
                              hipStream_t stream) {
  const float* fout = (const float*)d_in[0];
  const float* hn   = (const float*)d_in[1];
  const float* h0   = (const float*)d_in[2];
  const float* k3w1 = (const float*)d_in[3];
  const float* k3s1 = (const float*)d_in[4];
  const float* k3b1 = (const float*)d_in[5];
  const float* k3w2 = (const float*)d_in[6];
  const float* k3s2 = (const float*)d_in[7];
  const float* k3b2 = (const float*)d_in[8];
  const float* k5w1 = (const float*)d_in[9];
  const float* k5s1 = (const float*)d_in[10];
  const float* k5b1 = (const float*)d_in[11];
  const float* k5w2 = (const float*)d_in[12];
  const float* k5s2 = (const float*)d_in[13];
  const float* k5b2 = (const float*)d_in[14];
  const float* k7w1 = (const float*)d_in[15];
  const float* k7s1 = (const float*)d_in[16];
  const float* k7b1 = (const float*)d_in[17];
  const float* k7w2 = (const float*)d_in[18];
  const float* k7s2 = (const float*)d_in[19];
  const float* k7b2 = (const float*)d_in[20];
  const float* mw1  = (const float*)d_in[21];
  const float* ms1  = (const float*)d_in[22];
  const float* mb1  = (const float*)d_in[23];
  const float* mw2  = (const float*)d_in[24];
  const float* mbias2 = (const float*)d_in[25];
  const float* cw1  = (const float*)d_in[26];
  const float* cs1  = (const float*)d_in[27];
  const float* cb1  = (const float*)d_in[28];
  const float* cw2  = (const float*)d_in[29];
  const float* cbias2 = (const float*)d_in[30];
  const float* tw1  = (const float*)d_in[31];
  const float* ts1  = (const float*)d_in[32];
  const float* tb1  = (const float*)d_in[33];
  const float* tw2  = (const float*)d_in[34];
  const float* tbias2 = (const float*)d_in[35];

  float* out = (float*)d_out;

  // workspace: hP padded bf16 (2*HWP*32) + w planes bf16 (80*NP) +
  //            fp32 mask/conf/hA/hns (15*NP). ~177 MB (proven-safe <= 203).
  size_t hP_elems = (size_t)2 * HWP * 32;
  size_t need = hP_elems * 2 + (size_t)NP * (80 * 2 + 15 * 4);
  if (ws_size < need) return;
  ushort* hPb  = (ushort*)d_ws;            // padded h, NHWC bf16
  ushort* w3   = hPb  + hP_elems;          // 8*NP  bf16 NCHW (no mid)
  ushort* w5   = w3   + (size_t)8 * NP;    // 24*NP
  ushort* w7   = w5   + (size_t)24 * NP;   // 48*NP
  float* mask  = (float*)(w7 + (size_t)48 * NP);  // 3*NP f32
  float* conf  = mask + (size_t)3 * NP;    // 3*NP f32
  float* hA    = conf + (size_t)3 * NP;    // 6*NP f32 ping-pong
  float* hns   = hA   + (size_t)6 * NP;    // 3*NP f32

  dim3 blk(256);
  dim3 gc(W_ / 64, H_ / 4, B_);   // 19 x 64 x 2
  int ge = NP / 256;
  constexpr int PB = 2 * WP * 4 + 2 * (HP - 2) * 4;
  int gz = (2 * PB + 255) / 256;

  zring_k<<<gz, blk, 0, stream>>>(hPb);

  // kernel-generator branches: split-precision conv1 + conv2
  convs1<<<gc, blk, 0, stream>>>(fout, k3w1, k3s1, k3b1, hPb);
  convs2<1, 4><<<gc, blk, 0, stream>>>(hPb, k3w2, k3s2, k3b2, w3, 8);
  convs1<<<gc, blk, 0, stream>>>(fout, k5w1, k5s1, k5b1, hPb);
  convs2<2, 2><<<gc, blk, 0, stream>>>(hPb, k5w2, k5s2, k5b2, w5, 24);
  convs1<<<gc, blk, 0, stream>>>(fout, k7w1, k7s1, k7b1, hPb);
  convs2<3, 2><<<gc, blk, 0, stream>>>(hPb, k7w2, k7s2, k7b2, w7, 48);

  // mask branch
  conv1p<0, 3><<<gc, blk, 0, stream>>>(fout, nullptr, mw1, ms1, mb1, hPb);
  conv2g<2><<<gc, blk, 0, stream>>>(hPb, mw2, mbias2, h0, nullptr, mask);

  // confidence branch
  conv1p<0, 3><<<gc, blk, 0, stream>>>(fout, nullptr, cw1, cs1, cb1, hPb);
  conv2g<3><<<gc, blk, 0, stream>>>(hPb, cw2, cbias2, nullptr, nullptr, conf);

  // propagation
  float* h3c = hA + (size_t)0 * NP; float* h3n = hA + (size_t)1 * NP;
  float* h5c = hA + (size_t)2 * NP; float* h5n = hA + (size_t)3 * NP;
  float* h7c = hA + (size_t)4 * NP; float* h7n = hA + (size_t)5 * NP;

  init_k<<<ge, blk, 0, stream>>>(hn, h3c, h5c, h7c, hns);
  for (int i = 0; i < 6; ++i) {
    int chn = (i == 2) ? 1 : ((i == 5) ? 2 : -1);
    iterate_k<<<ge, blk, 0, stream>>>(h3c, h5c, h7c, h3n, h5n, h7n,
                                      w3, w5, w7, mask, h0, hns, chn, conf);
    float* t;
    t = h3c; h3c = h3n; h3n = t;
    t = h5c; h5c = h5n; h5n = t;
    t = h7c; h7c = h7n; h7n = t;
  }

  // final temporal-weight branch
  conv1p<1, 2><<<gc, blk, 0, stream>>>(fout, hns, tw1, ts1, tb1, hPb);
  conv2g<4><<<gc, blk, 0, stream>>>(hPb, tw2, tbias2, nullptr, hns, out);
}

// Round 9
// 910.729 us; speedup vs baseline: 3.2783x; 1.1432x over previous
//
#include <hip/hip_runtime.h>
#include <hip/hip_bf16.h>

constexpr int B_ = 2, H_ = 256, W_ = 1216;
constexpr int HW = H_ * W_;          // 311296
constexpr int NP = B_ * HW;          // 622592
constexpr int WP = W_ + 2;           // 1218 padded width
constexpr int HP = H_ + 2;           // 258  padded height
constexpr int HWP = HP * WP;         // 314244
constexpr float EPS_ = 1e-6f;

// prepped-weight region offsets (ushort units)
constexpr int PW1_K3 = 0;                    // [2][9][32][32] hi/lo
constexpr int PW1_K5 = 18432;
constexpr int PW1_K7 = 36864;
constexpr int PW2_K3 = 55296;                // [2][9][16][32]
constexpr int PW2_K5 = 64512;                // [2][9][32][32]
constexpr int PW2_K7 = 82944;                // [2][9][48][32]
constexpr int PP1_M  = 110592;               // [9][32][32] plain
constexpr int PP1_C  = 119808;
constexpr int PP1_T  = 129024;
constexpr int PP1T2  = 138240;               // [9][32][8]
constexpr int PG2_M  = 140544;               // [9][16][32] plain
constexpr int PG2_C  = 145152;
constexpr int PG2_T  = 149760;
constexpr int PREP_N = 154368;

typedef __bf16 bfrag __attribute__((ext_vector_type(8)));
typedef float f4 __attribute__((ext_vector_type(4)));

union BU { uint4 u; bfrag f; };

__device__ __forceinline__ ushort f2b(float x) {
  uint u = __float_as_uint(x);
  u += 0x7fffu + ((u >> 16) & 1u);
  return (ushort)(u >> 16);
}
__device__ __forceinline__ float b2f(ushort u) {
  return __uint_as_float(((uint)u) << 16);
}

// ---------------------------------------------------------------------------
// One-shot weight prep: OIHW fp32 -> fragment-ready bf16 layouts (hi/lo
// precomputed, CO-padding zeroed). Removes the per-block stride-9 gather +
// convert + LDS round-trip from every conv kernel.
// ---------------------------------------------------------------------------
__global__ __launch_bounds__(256)
void prep_k(const float* __restrict__ k3w1, const float* __restrict__ k5w1,
            const float* __restrict__ k7w1, const float* __restrict__ k3w2,
            const float* __restrict__ k5w2, const float* __restrict__ k7w2,
            const float* __restrict__ mw1, const float* __restrict__ cw1,
            const float* __restrict__ tw1, const float* __restrict__ mw2,
            const float* __restrict__ cw2, const float* __restrict__ tw2,
            ushort* __restrict__ wp)
{
  int i = blockIdx.x * 256 + threadIdx.x;
  if (i >= PREP_N) return;
  ushort outv;
  if (i < PW2_K3) {                       // conv1 chains hi/lo [c][2][9][32][32]
    int c = i / 18432, r = i % 18432;
    const float* src = (c == 0) ? k3w1 : (c == 1) ? k5w1 : k7w1;
    int ci = r & 31; int t1 = r >> 5;
    int co = t1 & 31; int t2 = t1 >> 5;
    int tap = t2 % 9, half = t2 / 9;
    float v = src[(co * 32 + ci) * 9 + tap];
    ushort hi = f2b(v);
    outv = half ? f2b(v - b2f(hi)) : hi;
  } else if (i < PP1_M) {                 // conv2 chains [2][9][NM16][32]
    int r = i - PW2_K3;
    const float* src; int NM16, CO;
    if (r < 9216)       { src = k3w2; NM16 = 16; CO = 8; }
    else if (r < 27648) { src = k5w2; NM16 = 32; CO = 24; r -= 9216; }
    else                { src = k7w2; NM16 = 48; CO = 48; r -= 27648; }
    int ci = r & 31; int t1 = r >> 5;
    int co = t1 % NM16; int t2 = t1 / NM16;
    int tap = t2 % 9, half = t2 / 9;
    if (co < CO) {
      float v = src[(co * 32 + ci) * 9 + tap];
      ushort hi = f2b(v);
      outv = half ? f2b(v - b2f(hi)) : hi;
    } else outv = 0;
  } else if (i < PP1T2) {                 // conv1p plain [c][9][32][32]
    int r = i - PP1_M;
    int c = r / 9216; r %= 9216;
    const float* src = (c == 0) ? mw1 : (c == 1) ? cw1 : tw1;
    int CIN = (c == 2) ? 35 : 32;
    int ci = r & 31; int t1 = r >> 5;
    int co = t1 & 31, tap = t1 >> 5;
    outv = f2b(src[(co * CIN + ci) * 9 + tap]);
  } else if (i < PG2_M) {                 // t-branch extra K [9][32][8]
    int r = i - PP1T2;
    int c8 = r & 7; int t1 = r >> 3;
    int co = t1 & 31, tap = t1 >> 5;
    int cc = (c8 < 3) ? c8 : ((c8 < 6) ? c8 - 3 : -1);
    outv = (cc >= 0) ? f2b(tw1[(co * 35 + 32 + cc) * 9 + tap]) : (ushort)0;
  } else {                                // conv2g [c][9][16][32]
    int r = i - PG2_M;
    int c = r / 4608; r %= 4608;
    const float* src = (c == 0) ? mw2 : (c == 1) ? cw2 : tw2;
    int ci = r & 31; int t1 = r >> 5;
    int co = t1 & 15, tap = t1 >> 4;
    outv = (co < 3) ? f2b(src[(co * 32 + ci) * 9 + tap]) : (ushort)0;
  }
  wp[i] = outv;
}

// ---------------------------------------------------------------------------
// Zero the pad ring of hP (padded NHWC bf16 [b][HP][WP][32]).
// ---------------------------------------------------------------------------
__global__ __launch_bounds__(256)
void zring_k(ushort* __restrict__ hP) {
  constexpr int PB = 2 * WP * 4 + 2 * (HP - 2) * 4;   // uint4 units per batch
  int i = blockIdx.x * 256 + threadIdx.x;
  if (i >= 2 * PB) return;
  int b = i / PB, r = i % PB;
  size_t idx;
  if (r < WP * 4) idx = (size_t)r;
  else if (r < 2 * WP * 4) idx = (size_t)(HP - 1) * WP * 4 + (r - WP * 4);
  else {
    int q = r - 2 * WP * 4;
    int row = q >> 3, k = q & 7;
    int col = (k < 4) ? k : (WP - 1) * 4 + (k - 4);
    idx = (size_t)(row + 1) * WP * 4 + col;
  }
  *(uint4*)&hP[(size_t)b * HWP * 32 + idx * 8] = uint4{0, 0, 0, 0};
}

// ---------------------------------------------------------------------------
// Split-precision conv1 (w-chains): fout(fp32 NCHW) -> hP(bf16 padded NHWC).
// acc = Whi*Xhi + Whi*Xlo + Wlo*Xhi. Weights streamed per tap from prepped
// global (coalesced 1KB/wave); LDS holds only the hi/lo input tile; 1 barrier.
// ---------------------------------------------------------------------------
__global__ __launch_bounds__(256, 3)
void convs1(const float* __restrict__ xf, const ushort* __restrict__ wp,
            const float* __restrict__ scale, const float* __restrict__ bias,
            ushort* __restrict__ outh)
{
  __shared__ ushort xl[25344];   // hi [0,12672) | lo [12672,25344)

  const int tid = threadIdx.x;
  const int lane = tid & 63;
  const int wid = tid >> 6;
  const int x0 = blockIdx.x * 64, y0 = blockIdx.y * 4, b = blockIdx.z;

  for (int i = tid; i < 396 * 4; i += 256) {
    int oct = i & 3, rest = i >> 2;
    int xx = rest % 66, rr = rest / 66;
    int yy = y0 - 1 + rr, x = x0 - 1 + xx;
    uint4 vh = {0, 0, 0, 0}, vl = {0, 0, 0, 0};
    if ((unsigned)yy < (unsigned)H_ && (unsigned)x < (unsigned)W_) {
      const float* src = xf + ((size_t)b * 32 + oct * 8) * HW + (size_t)yy * W_ + x;
      uint uh[4], ul[4];
#pragma unroll
      for (int j = 0; j < 4; ++j) {
        float a = src[(size_t)(2 * j + 0) * HW];
        float c = src[(size_t)(2 * j + 1) * HW];
        ushort ah = f2b(a), ch = f2b(c);
        ushort al = f2b(a - b2f(ah)), cl = f2b(c - b2f(ch));
        uh[j] = (uint)ah | ((uint)ch << 16);
        ul[j] = (uint)al | ((uint)cl << 16);
      }
      vh = uint4{uh[0], uh[1], uh[2], uh[3]};
      vl = uint4{ul[0], ul[1], ul[2], ul[3]};
    }
    *(uint4*)&xl[rest * 32 + oct * 8] = vh;
    *(uint4*)&xl[12672 + rest * 32 + oct * 8] = vl;
  }
  __syncthreads();

  const int n = lane & 15, quad = lane >> 4;

  f4 acc[4][2];
#pragma unroll
  for (int tu = 0; tu < 4; ++tu)
#pragma unroll
    for (int mt = 0; mt < 2; ++mt) acc[tu][mt] = f4{0.f, 0.f, 0.f, 0.f};

#pragma unroll
  for (int tap = 0; tap < 9; ++tap) {
    int dy = tap / 3, dx = tap % 3;
    bfrag avhi[2], avlo[2];
#pragma unroll
    for (int mt = 0; mt < 2; ++mt) {
      avhi[mt] = *(const bfrag*)&wp[((tap * 32) + mt * 16 + n) * 32 + quad * 8];
      avlo[mt] = *(const bfrag*)&wp[(((9 + tap) * 32) + mt * 16 + n) * 32 + quad * 8];
    }
#pragma unroll
    for (int tu = 0; tu < 4; ++tu) {
      int t = wid + tu * 4;
      int r = t >> 2, g = t & 3;
      int pix = (r + dy) * 66 + g * 16 + n + dx;
      bfrag bhi = *(const bfrag*)&xl[pix * 32 + quad * 8];
      bfrag blo = *(const bfrag*)&xl[12672 + pix * 32 + quad * 8];
#pragma unroll
      for (int mt = 0; mt < 2; ++mt) {
        acc[tu][mt] = __builtin_amdgcn_mfma_f32_16x16x32_bf16(avhi[mt], bhi, acc[tu][mt], 0, 0, 0);
        acc[tu][mt] = __builtin_amdgcn_mfma_f32_16x16x32_bf16(avhi[mt], blo, acc[tu][mt], 0, 0, 0);
        acc[tu][mt] = __builtin_amdgcn_mfma_f32_16x16x32_bf16(avlo[mt], bhi, acc[tu][mt], 0, 0, 0);
      }
    }
  }

#pragma unroll
  for (int tu = 0; tu < 4; ++tu) {
    int t = wid + tu * 4;
    int r = t >> 2, g = t & 3;
    int gx = x0 + g * 16 + n, gy = y0 + r;
    size_t bpix = (size_t)b * HWP + (size_t)(gy + 1) * WP + (gx + 1);
#pragma unroll
    for (int mt = 0; mt < 2; ++mt) {
      int cob = mt * 16 + quad * 4;
      float v0 = fmaxf(acc[tu][mt][0] * scale[cob + 0] + bias[cob + 0], 0.f);
      float v1 = fmaxf(acc[tu][mt][1] * scale[cob + 1] + bias[cob + 1], 0.f);
      float v2 = fmaxf(acc[tu][mt][2] * scale[cob + 2] + bias[cob + 2], 0.f);
      float v3 = fmaxf(acc[tu][mt][3] * scale[cob + 3] + bias[cob + 3], 0.f);
      uint u0 = (uint)f2b(v0) | ((uint)f2b(v1) << 16);
      uint u1 = (uint)f2b(v2) | ((uint)f2b(v3) << 16);
      *(uint2*)&outh[bpix * 32 + cob] = uint2{u0, u1};
    }
  }
}

// ---------------------------------------------------------------------------
// Split-precision conv2 (w-chains): LDS-free, barrier-free. Weights (hi/lo)
// streamed per tap from prep; B direct from padded hP. Epilogue: normalize.
// ---------------------------------------------------------------------------
template<int nM, int MINW>
__global__ __launch_bounds__(256, MINW)
void convs2(const ushort* __restrict__ hP, const ushort* __restrict__ wp,
            const float* __restrict__ scale, const float* __restrict__ bias,
            ushort* __restrict__ outw, int CO)
{
  constexpr int NM16 = nM * 16;
  const int tid = threadIdx.x;
  const int lane = tid & 63;
  const int wid = tid >> 6;
  const int x0 = blockIdx.x * 64, y0 = blockIdx.y * 4, b = blockIdx.z;

  const int n = lane & 15, quad = lane >> 4;
  const ushort* hb = hP + (size_t)b * HWP * 32;

  f4 acc[4][nM];
#pragma unroll
  for (int tu = 0; tu < 4; ++tu)
#pragma unroll
    for (int mt = 0; mt < nM; ++mt) acc[tu][mt] = f4{0.f, 0.f, 0.f, 0.f};

#pragma unroll
  for (int tap = 0; tap < 9; ++tap) {
    int dy = tap / 3, dx = tap % 3;
    bfrag whi[nM], wlo[nM];
#pragma unroll
    for (int mt = 0; mt < nM; ++mt) {
      whi[mt] = *(const bfrag*)&wp[((tap * NM16) + mt * 16 + n) * 32 + quad * 8];
      wlo[mt] = *(const bfrag*)&wp[((9 * NM16) + tap * NM16 + mt * 16 + n) * 32 + quad * 8];
    }
#pragma unroll
    for (int tu = 0; tu < 4; ++tu) {
      int t = wid + tu * 4;
      int r = t >> 2, g = t & 3;
      int rb = (y0 + r + dy) * WP + x0 + g * 16 + n + dx;
      bfrag bv = *(const bfrag*)&hb[(size_t)rb * 32 + quad * 8];
#pragma unroll
      for (int mt = 0; mt < nM; ++mt) {
        acc[tu][mt] = __builtin_amdgcn_mfma_f32_16x16x32_bf16(whi[mt], bv, acc[tu][mt], 0, 0, 0);
        acc[tu][mt] = __builtin_amdgcn_mfma_f32_16x16x32_bf16(wlo[mt], bv, acc[tu][mt], 0, 0, 0);
      }
    }
  }

#pragma unroll
  for (int tu = 0; tu < 4; ++tu) {
    int t = wid + tu * 4;
    int r = t >> 2, g = t & 3;
    int gx = x0 + g * 16 + n, gy = y0 + r;
    size_t gpix = (size_t)gy * W_ + gx;

    float vs[nM][4];
    float pa = 0.f;
#pragma unroll
    for (int mt = 0; mt < nM; ++mt)
#pragma unroll
      for (int rg = 0; rg < 4; ++rg) {
        int co = mt * 16 + quad * 4 + rg;
        float v = (co < CO) ? acc[tu][mt][rg] * scale[co] + bias[co] : 0.f;
        vs[mt][rg] = v;
        pa += fabsf(v);
      }
    pa += __shfl_xor(pa, 16);
    pa += __shfl_xor(pa, 32);
    float inv = 1.f / (pa + EPS_);
#pragma unroll
    for (int mt = 0; mt < nM; ++mt)
#pragma unroll
      for (int rg = 0; rg < 4; ++rg) {
        int co = mt * 16 + quad * 4 + rg;
        if (co < CO)
          outw[((size_t)b * CO + co) * HW + gpix] = f2b(vs[mt][rg] * inv);
      }
  }
}

// ---------------------------------------------------------------------------
// Plain bf16 conv1 (mask/conf/t): fout(fp32 NCHW) -> hP (padded). Weights
// streamed from prep; LDS = input tile (+ hns hi/lo tile for KB2); 1 barrier.
// ---------------------------------------------------------------------------
template<int KB2, int MINW>
__global__ __launch_bounds__(256, MINW)
void conv1p(const float* __restrict__ xf, const float* __restrict__ hnsp,
            const ushort* __restrict__ wp, const ushort* __restrict__ wp2,
            const float* __restrict__ scale, const float* __restrict__ bias,
            ushort* __restrict__ outh)
{
  __shared__ ushort xl[396 * 32];
  __shared__ ushort xl2[KB2 ? 396 * 8 : 8];

  const int tid = threadIdx.x;
  const int lane = tid & 63;
  const int wid = tid >> 6;
  const int x0 = blockIdx.x * 64, y0 = blockIdx.y * 4, b = blockIdx.z;

  if (KB2) {
    for (int i = tid; i < 396; i += 256) {
      int xx = i % 66, rr = i / 66;
      int yy = y0 - 1 + rr, x = x0 - 1 + xx;
      float v0 = 0.f, v1 = 0.f, v2 = 0.f;
      if ((unsigned)yy < (unsigned)H_ && (unsigned)x < (unsigned)W_) {
        size_t pix = (size_t)yy * W_ + x;
        v0 = hnsp[((size_t)b * 3 + 0) * HW + pix];
        v1 = hnsp[((size_t)b * 3 + 1) * HW + pix];
        v2 = hnsp[((size_t)b * 3 + 2) * HW + pix];
      }
      ushort h0b = f2b(v0), h1b = f2b(v1), h2b = f2b(v2);
      ushort l0 = f2b(v0 - b2f(h0b)), l1 = f2b(v1 - b2f(h1b)), l2 = f2b(v2 - b2f(h2b));
      uint u0 = (uint)h0b | ((uint)h1b << 16);
      uint u1 = (uint)h2b | ((uint)l0 << 16);
      uint u2 = (uint)l1 | ((uint)l2 << 16);
      *(uint4*)&xl2[i * 8] = uint4{u0, u1, u2, 0};
    }
  }
  for (int i = tid; i < 396 * 4; i += 256) {
    int oct = i & 3, rest = i >> 2;
    int xx = rest % 66, rr = rest / 66;
    int yy = y0 - 1 + rr, x = x0 - 1 + xx;
    uint4 v = {0, 0, 0, 0};
    if ((unsigned)yy < (unsigned)H_ && (unsigned)x < (unsigned)W_) {
      const float* src = xf + ((size_t)b * 32 + oct * 8) * HW + (size_t)yy * W_ + x;
      uint u[4];
#pragma unroll
      for (int j = 0; j < 4; ++j) {
        float a = src[(size_t)(2 * j + 0) * HW];
        float c = src[(size_t)(2 * j + 1) * HW];
        u[j] = (uint)f2b(a) | ((uint)f2b(c) << 16);
      }
      v = uint4{u[0], u[1], u[2], u[3]};
    }
    *(uint4*)&xl[rest * 32 + oct * 8] = v;
  }
  __syncthreads();

  const int n = lane & 15, quad = lane >> 4;

  f4 acc[4][2];
#pragma unroll
  for (int tu = 0; tu < 4; ++tu)
#pragma unroll
    for (int mt = 0; mt < 2; ++mt) acc[tu][mt] = f4{0.f, 0.f, 0.f, 0.f};

#pragma unroll
  for (int tap = 0; tap < 9; ++tap) {
    int dy = tap / 3, dx = tap % 3;
    bfrag av[2];
#pragma unroll
    for (int mt = 0; mt < 2; ++mt)
      av[mt] = *(const bfrag*)&wp[((tap * 32) + mt * 16 + n) * 32 + quad * 8];
    bfrag a2[KB2 ? 2 : 1];
    if (KB2) {
#pragma unroll
      for (int mt = 0; mt < 2; ++mt) {
        BU t; t.u = uint4{0, 0, 0, 0};
        if (lane < 16) t.f = *(const bfrag*)&wp2[(tap * 32 + mt * 16 + lane) * 8];
        a2[mt] = t.f;
      }
    }
#pragma unroll
    for (int tu = 0; tu < 4; ++tu) {
      int t = wid + tu * 4;
      int r = t >> 2, g = t & 3;
      int pix = (r + dy) * 66 + g * 16 + n + dx;
      bfrag bv = *(const bfrag*)&xl[pix * 32 + quad * 8];
#pragma unroll
      for (int mt = 0; mt < 2; ++mt)
        acc[tu][mt] = __builtin_amdgcn_mfma_f32_16x16x32_bf16(av[mt], bv, acc[tu][mt], 0, 0, 0);
      if (KB2) {
        BU t2; t2.u = uint4{0, 0, 0, 0};
        if (lane < 16) t2.f = *(const bfrag*)&xl2[pix * 8];
#pragma unroll
        for (int mt = 0; mt < 2; ++mt)
          acc[tu][mt] = __builtin_amdgcn_mfma_f32_16x16x32_bf16(a2[mt], t2.f, acc[tu][mt], 0, 0, 0);
      }
    }
  }

#pragma unroll
  for (int tu = 0; tu < 4; ++tu) {
    int t = wid + tu * 4;
    int r = t >> 2, g = t & 3;
    int gx = x0 + g * 16 + n, gy = y0 + r;
    size_t bpix = (size_t)b * HWP + (size_t)(gy + 1) * WP + (gx + 1);
#pragma unroll
    for (int mt = 0; mt < 2; ++mt) {
      int cob = mt * 16 + quad * 4;
      float v0 = fmaxf(acc[tu][mt][0] * scale[cob + 0] + bias[cob + 0], 0.f);
      float v1 = fmaxf(acc[tu][mt][1] * scale[cob + 1] + bias[cob + 1], 0.f);
      float v2 = fmaxf(acc[tu][mt][2] * scale[cob + 2] + bias[cob + 2], 0.f);
      float v3 = fmaxf(acc[tu][mt][3] * scale[cob + 3] + bias[cob + 3], 0.f);
      uint u0 = (uint)f2b(v0) | ((uint)f2b(v1) << 16);
      uint u1 = (uint)f2b(v2) | ((uint)f2b(v3) << 16);
      *(uint2*)&outh[bpix * 32 + cob] = uint2{u0, u1};
    }
  }
}

// ---------------------------------------------------------------------------
// Small conv2 (CO=3): LDS-free, barrier-free; 9 weight frags resident.
// EPI: 2 mask; 3 conf; 4 final dot with hns.
// ---------------------------------------------------------------------------
template<int EPI>
__global__ __launch_bounds__(256, 4)
void conv2g(const ushort* __restrict__ hP, const ushort* __restrict__ wp,
            const float* __restrict__ bias, const float* __restrict__ h0,
            const float* __restrict__ hnsp, float* __restrict__ outf)
{
  const int tid = threadIdx.x;
  const int lane = tid & 63;
  const int wid = tid >> 6;
  const int x0 = blockIdx.x * 64, y0 = blockIdx.y * 4, b = blockIdx.z;
  const int n = lane & 15, quad = lane >> 4;

  bfrag av[9];
#pragma unroll
  for (int tap = 0; tap < 9; ++tap)
    av[tap] = *(const bfrag*)&wp[((tap * 16) + n) * 32 + quad * 8];

  const ushort* hb = hP + (size_t)b * HWP * 32;

  f4 acc[4];
#pragma unroll
  for (int tu = 0; tu < 4; ++tu) acc[tu] = f4{0.f, 0.f, 0.f, 0.f};

#pragma unroll
  for (int tap = 0; tap < 9; ++tap) {
    int dy = tap / 3, dx = tap % 3;
#pragma unroll
    for (int tu = 0; tu < 4; ++tu) {
      int t = wid + tu * 4;
      int r = t >> 2, g = t & 3;
      int rb = (y0 + r + dy) * WP + x0 + g * 16 + n + dx;
      bfrag bv = *(const bfrag*)&hb[(size_t)rb * 32 + quad * 8];
      acc[tu] = __builtin_amdgcn_mfma_f32_16x16x32_bf16(av[tap], bv, acc[tu], 0, 0, 0);
    }
  }

#pragma unroll
  for (int tu = 0; tu < 4; ++tu) {
    int t = wid + tu * 4;
    int r = t >> 2, g = t & 3;
    int gx = x0 + g * 16 + n, gy = y0 + r;
    size_t gpix = (size_t)gy * W_ + gx;
    size_t bpix = (size_t)b * HW + gpix;

    if constexpr (EPI == 2) {
      if (lane < 16) {
        float valid = (h0[bpix] > 0.001f) ? 1.f : 0.f;
#pragma unroll
        for (int rg = 0; rg < 3; ++rg) {
          float v = acc[tu][rg] + bias[rg];
          float sg = 1.f / (1.f + expf(-v));
          outf[((size_t)b * 3 + rg) * HW + gpix] = sg * valid;
        }
      }
    } else if constexpr (EPI == 3) {
      if (lane < 16) {
        float v0 = acc[tu][0] + bias[0];
        float v1 = acc[tu][1] + bias[1];
        float v2 = acc[tu][2] + bias[2];
        float m = fmaxf(v0, fmaxf(v1, v2));
        float e0 = expf(v0 - m), e1 = expf(v1 - m), e2 = expf(v2 - m);
        float inv = 1.f / (e0 + e1 + e2);
        outf[((size_t)b * 3 + 0) * HW + gpix] = e0 * inv;
        outf[((size_t)b * 3 + 1) * HW + gpix] = e1 * inv;
        outf[((size_t)b * 3 + 2) * HW + gpix] = e2 * inv;
      }
    } else if constexpr (EPI == 4) {
      if (lane < 16) {
        float v0 = acc[tu][0] + bias[0];
        float v1 = acc[tu][1] + bias[1];
        float v2 = acc[tu][2] + bias[2];
        float m = fmaxf(v0, fmaxf(v1, v2));
        float e0 = expf(v0 - m), e1 = expf(v1 - m), e2 = expf(v2 - m);
        float inv = 1.f / (e0 + e1 + e2);
        float a0 = hnsp[((size_t)b * 3 + 0) * HW + gpix];
        float a1 = hnsp[((size_t)b * 3 + 1) * HW + gpix];
        float a2v = hnsp[((size_t)b * 3 + 2) * HW + gpix];
        outf[bpix] = (e0 * a0 + e1 * a1 + e2 * a2v) * inv;
      }
    }
  }
}

// ---------------------------------------------------------------------------
__global__ __launch_bounds__(256)
void init_k(const float* __restrict__ hn, float* __restrict__ h3,
            float* __restrict__ h5, float* __restrict__ h7,
            float* __restrict__ hns)
{
  int t = blockIdx.x * 256 + threadIdx.x;
  if (t >= NP) return;
  float v = hn[t];
  h3[t] = v; h5[t] = v; h7[t] = v;
  int b = t / HW, rem = t - b * HW;
  hns[(size_t)b * 3 * HW + rem] = v;
}

// ---------------------------------------------------------------------------
// Propagation step. w planes bf16 w/o mid; mid = 1 - sum (fp32 recompute).
// State fp32 (values reach ~200; bf16 state was the R3 failure).
// ---------------------------------------------------------------------------
__global__ __launch_bounds__(256)
void iterate_k(const float* __restrict__ h3i, const float* __restrict__ h5i,
               const float* __restrict__ h7i,
               float* __restrict__ h3o, float* __restrict__ h5o,
               float* __restrict__ h7o,
               const ushort* __restrict__ w3, const ushort* __restrict__ w5,
               const ushort* __restrict__ w7,
               const float* __restrict__ mask, const float* __restrict__ h0,
               float* __restrict__ hns, int chn, const float* __restrict__ conf)
{
  int t = blockIdx.x * 256 + threadIdx.x;
  if (t >= NP) return;
  int b = t / HW;
  int rem = t - b * HW;
  int y = rem / W_;
  int x = rem - y * W_;
  size_t pb = (size_t)b * HW;

  float h0v = h0[t];

  float s3 = 0.f, ws3 = 0.f;
#pragma unroll
  for (int p = 0; p < 8; ++p) {
    int tap = (p < 4) ? p : p + 1;
    int dy = tap / 3 - 1, dx = tap % 3 - 1;
    int yy = y + dy, xx = x + dx;
    float hv = ((unsigned)yy < (unsigned)H_ && (unsigned)xx < (unsigned)W_)
                   ? h3i[pb + yy * W_ + xx] : 0.f;
    float wv = b2f(w3[(size_t)(b * 8 + p) * HW + rem]);
    ws3 += wv;
    s3 += wv * hv;
  }
  s3 += (1.f - ws3) * h3i[t];
  float m3 = mask[(size_t)(b * 3 + 0) * HW + rem];
  float n3 = (1.f - m3) * s3 + m3 * h0v;
  h3o[t] = n3;

  float s5 = 0.f, ws5 = 0.f;
#pragma unroll
  for (int p = 0; p < 24; ++p) {
    int tap = (p < 12) ? p : p + 1;
    int dy = tap / 5 - 2, dx = tap % 5 - 2;
    int yy = y + dy, xx = x + dx;
    float hv = ((unsigned)yy < (unsigned)H_ && (unsigned)xx < (unsigned)W_)
                   ? h5i[pb + yy * W_ + xx] : 0.f;
    float wv = b2f(w5[(size_t)(b * 24 + p) * HW + rem]);
    ws5 += wv;
    s5 += wv * hv;
  }
  s5 += (1.f - ws5) * h5i[t];
  float m5 = mask[(size_t)(b * 3 + 1) * HW + rem];
  float n5 = (1.f - m5) * s5 + m5 * h0v;
  h5o[t] = n5;

  float s7 = 0.f, ws7 = 0.f;
#pragma unroll
  for (int p = 0; p < 48; ++p) {
    int tap = (p < 24) ? p : p + 1;
    int dy = tap / 7 - 3, dx = tap % 7 - 3;
    int yy = y + dy, xx = x + dx;
    float hv = ((unsigned)yy < (unsigned)H_ && (unsigned)xx < (unsigned)W_)
                   ? h7i[pb + yy * W_ + xx] : 0.f;
    float wv = b2f(w7[(size_t)(b * 48 + p) * HW + rem]);
    ws7 += wv;
    s7 += wv * hv;
  }
  s7 += (1.f - ws7) * h7i[t];
  float m7 = mask[(size_t)(b * 3 + 2) * HW + rem];
  float n7 = (1.f - m7) * s7 + m7 * h0v;
  h7o[t] = n7;

  if (chn >= 0) {
    float c3 = conf[(size_t)(b * 3 + 0) * HW + rem];
    float c5 = conf[(size_t)(b * 3 + 1) * HW + rem];
    float c7 = conf[(size_t)(b * 3 + 2) * HW + rem];
    hns[(size_t)(b * 3 + chn) * HW + rem] = c3 * n3 + c5 * n5 + c7 * n7;
  }
}

extern "C" void kernel_launch(void* const* d_in, const int* in_sizes, int n_in,
                              void* d_out, int out_size, void* d_ws, size_t ws_size,
                              hipStream_t stream) {
  const float* fout = (const float*)d_in[0];
  const float* hn   = (const float*)d_in[1];
  const float* h0   = (const float*)d_in[2];
  const float* k3w1 = (const float*)d_in[3];
  const float* k3s1 = (const float*)d_in[4];
  const float* k3b1 = (const float*)d_in[5];
  const float* k3w2 = (const float*)d_in[6];
  const float* k3s2 = (const float*)d_in[7];
  const float* k3b2 = (const float*)d_in[8];
  const float* k5w1 = (const float*)d_in[9];
  const float* k5s1 = (const float*)d_in[10];
  const float* k5b1 = (const float*)d_in[11];
  const float* k5w2 = (const float*)d_in[12];
  const float* k5s2 = (const float*)d_in[13];
  const float* k5b2 = (const float*)d_in[14];
  const float* k7w1 = (const float*)d_in[15];
  const float* k7s1 = (const float*)d_in[16];
  const float* k7b1 = (const float*)d_in[17];
  const float* k7w2 = (const float*)d_in[18];
  const float* k7s2 = (const float*)d_in[19];
  const float* k7b2 = (const float*)d_in[20];
  const float* mw1  = (const float*)d_in[21];
  const float* ms1  = (const float*)d_in[22];
  const float* mb1  = (const float*)d_in[23];
  const float* mw2  = (const float*)d_in[24];
  const float* mbias2 = (const float*)d_in[25];
  const float* cw1  = (const float*)d_in[26];
  const float* cs1  = (const float*)d_in[27];
  const float* cb1  = (const float*)d_in[28];
  const float* cw2  = (const float*)d_in[29];
  const float* cbias2 = (const float*)d_in[30];
  const float* tw1  = (const float*)d_in[31];
  const float* ts1  = (const float*)d_in[32];
  const float* tb1  = (const float*)d_in[33];
  const float* tw2  = (const float*)d_in[34];
  const float* tbias2 = (const float*)d_in[35];

  float* out = (float*)d_out;

  // workspace: hP padded bf16 + w planes bf16 + fp32 mask/conf/hA/hns + wprep
  size_t hP_elems = (size_t)2 * HWP * 32;
  size_t need = hP_elems * 2 + (size_t)NP * (80 * 2 + 15 * 4) + (size_t)PREP_N * 2;
  if (ws_size < need) return;
  ushort* hPb  = (ushort*)d_ws;            // padded h, NHWC bf16
  ushort* w3   = hPb  + hP_elems;          // 8*NP  bf16 NCHW (no mid)
  ushort* w5   = w3   + (size_t)8 * NP;    // 24*NP
  ushort* w7   = w5   + (size_t)24 * NP;   // 48*NP
  float* mask  = (float*)(w7 + (size_t)48 * NP);  // 3*NP f32
  float* conf  = mask + (size_t)3 * NP;    // 3*NP f32
  float* hA    = conf + (size_t)3 * NP;    // 6*NP f32 ping-pong
  float* hns   = hA   + (size_t)6 * NP;    // 3*NP f32
  ushort* wp   = (ushort*)(hns + (size_t)3 * NP); // PREP_N prepped weights

  dim3 blk(256);
  dim3 gc(W_ / 64, H_ / 4, B_);   // 19 x 64 x 2
  int ge = NP / 256;
  constexpr int PB = 2 * WP * 4 + 2 * (HP - 2) * 4;
  int gz = (2 * PB + 255) / 256;
  int gp = (PREP_N + 255) / 256;

  prep_k<<<gp, blk, 0, stream>>>(k3w1, k5w1, k7w1, k3w2, k5w2, k7w2,
                                 mw1, cw1, tw1, mw2, cw2, tw2, wp);
  zring_k<<<gz, blk, 0, stream>>>(hPb);

  // kernel-generator branches: split-precision conv1 + conv2
  convs1<<<gc, blk, 0, stream>>>(fout, wp + PW1_K3, k3s1, k3b1, hPb);
  convs2<1, 4><<<gc, blk, 0, stream>>>(hPb, wp + PW2_K3, k3s2, k3b2, w3, 8);
  convs1<<<gc, blk, 0, stream>>>(fout, wp + PW1_K5, k5s1, k5b1, hPb);
  convs2<2, 4><<<gc, blk, 0, stream>>>(hPb, wp + PW2_K5, k5s2, k5b2, w5, 24);
  convs1<<<gc, blk, 0, stream>>>(fout, wp + PW1_K7, k7s1, k7b1, hPb);
  convs2<3, 3><<<gc, blk, 0, stream>>>(hPb, wp + PW2_K7, k7s2, k7b2, w7, 48);

  // mask branch
  conv1p<0, 4><<<gc, blk, 0, stream>>>(fout, nullptr, wp + PP1_M, nullptr, ms1, mb1, hPb);
  conv2g<2><<<gc, blk, 0, stream>>>(hPb, wp + PG2_M, mbias2, h0, nullptr, mask);

  // confidence branch
  conv1p<0, 4><<<gc, blk, 0, stream>>>(fout, nullptr, wp + PP1_C, nullptr, cs1, cb1, hPb);
  conv2g<3><<<gc, blk, 0, stream>>>(hPb, wp + PG2_C, cbias2, nullptr, nullptr, conf);

  // propagation
  float* h3c = hA + (size_t)0 * NP; float* h3n = hA + (size_t)1 * NP;
  float* h5c = hA + (size_t)2 * NP; float* h5n = hA + (size_t)3 * NP;
  float* h7c = hA + (size_t)4 * NP; float* h7n = hA + (size_t)5 * NP;

  init_k<<<ge, blk, 0, stream>>>(hn, h3c, h5c, h7c, hns);
  for (int i = 0; i < 6; ++i) {
    int chn = (i == 2) ? 1 : ((i == 5) ? 2 : -1);
    iterate_k<<<ge, blk, 0, stream>>>(h3c, h5c, h7c, h3n, h5n, h7n,
                                      w3, w5, w7, mask, h0, hns, chn, conf);
    float* t;
    t = h3c; h3c = h3n; h3n = t;
    t = h5c; h5c = h5n; h5n = t;
    t = h7c; h7c = h7n; h7n = t;
  }

  // final temporal-weight branch
  conv1p<1, 3><<<gc, blk, 0, stream>>>(fout, hns, wp + PP1_T, wp + PP1T2, ts1, tb1, hPb);
  conv2g<4><<<gc, blk, 0, stream>>>(hPb, wp + PG2_T, tbias2, nullptr, hns, out);
}